// Round 7
// baseline (2095.949 us; speedup 1.0000x reference)
//
#include <hip/hip_runtime.h>

// ---------------------------------------------------------------------------
// R7: resident-weight LSTM scan with 1-barrier pipelined steps.
//  - fc_chunk: batched GEMM computes x = fc_in(seq) per 32-step t-chunk.
//  - scan_chunk: 256 blocks x 512 thr, 16 batch rows each. Iteration i
//    computes {cell2(i), cell1(i+1)} (both depend only on h1(i)) -> one
//    lgkm barrier/step. All reads hit parity-A LDS buffers, all writes
//    parity-B. Weights: wgt1[4][8]+wgt2v[4][4] in VGPRs (192), Whh2 in LDS
//    (128 KB). Bias pre-loaded into MFMA C-init. launch_bounds(512,1):
//    LDS already caps 1 block/CU; let allocator use 256 VGPRs (R6 bug:
//    cap 128 forced AGPR shuffling).
// ---------------------------------------------------------------------------

typedef unsigned short u16;
typedef short bf16x8 __attribute__((ext_vector_type(8)));
typedef float f32x4 __attribute__((ext_vector_type(4)));
typedef unsigned short u16x4 __attribute__((ext_vector_type(4)));

#define MFMA16(a, b, c) __builtin_amdgcn_mfma_f32_16x16x32_bf16((a), (b), (c), 0, 0, 0)

#define GLOAD_LDS(gp, lp) __builtin_amdgcn_global_load_lds( \
    (const __attribute__((address_space(1))) unsigned int*)(const void*)(gp), \
    (__attribute__((address_space(3))) unsigned int*)(void*)(lp), 16, 0, 0)

#define LGKM_BAR do { \
  asm volatile("s_waitcnt lgkmcnt(0)" ::: "memory"); \
  __builtin_amdgcn_sched_barrier(0); \
  __builtin_amdgcn_s_barrier(); \
  __builtin_amdgcn_sched_barrier(0); \
} while (0)

__device__ __forceinline__ u16 f2bf(float f) {
  union { float f; unsigned u; } v; v.f = f;
  return (u16)((v.u + 0x7FFFu + ((v.u >> 16) & 1u)) >> 16);  // RNE
}
__device__ __forceinline__ float fsig(float x) { return 1.0f / (1.0f + __expf(-x)); }
__device__ __forceinline__ float ftanh(float x) { return 2.0f / (1.0f + __expf(-2.0f * x)) - 1.0f; }

// ---- ws layout (u16 / f32 indices) ---------------------------------------
#define WC1_U   0         // 256 frags: ((w*4+g)*8+kf)*512
#define WC2V_U  131072    // 128 frags: ((w*4+g)*4+kf)*512 ; Wih2
#define WC2L_U  196608    // 128 frags: Whh2
#define W1_U    262144
#define W2_U    278528
#define W3_U    311296
#define WO1_U   327680
#define WO2_U   344064
#define WO3_U   376832
#define BS1_F   192512
#define BS2_F   193024
#define STH1_U  393216
#define STH2_U  917504
#define C1_F    720896
#define C2_F    1245184
#define XB_U    4194304   // bf16[32][4096][128] x chunk buffer (byte 8388608)
#define TC      32
#define NCH     8

// ======================= prep ==============================================
__global__ void prep_kernel(const float* __restrict__ Wih1, const float* __restrict__ Whh1,
                            const float* __restrict__ bih1, const float* __restrict__ bhh1,
                            const float* __restrict__ Wih2, const float* __restrict__ Whh2,
                            const float* __restrict__ bih2, const float* __restrict__ bhh2,
                            const float* __restrict__ W_in1, const float* __restrict__ W_in2,
                            const float* __restrict__ W_in3,
                            const float* __restrict__ W_out1, const float* __restrict__ W_out2,
                            const float* __restrict__ W_out3,
                            const float* __restrict__ h1_in, const float* __restrict__ h2_in,
                            const float* __restrict__ c1_in, const float* __restrict__ c2_in,
                            u16* __restrict__ wsu) {
  float* wsf = (float*)wsu;
  const int N_total = 2490368;
  int stride = gridDim.x * blockDim.x;
  for (int idx = blockIdx.x * blockDim.x + threadIdx.x; idx < N_total; idx += stride) {
    if (idx < 385024) {
      int within = idx & 511;
      int frag = (idx >> 9);
      int lane = within >> 3, e = within & 7;
      int lr = lane & 15, lg = lane >> 4;
      int k8 = lg * 8 + e;
      float v;
      if (idx < 131072) {                     // WC1
        int kf = frag & 7, g = (frag >> 3) & 3, w = frag >> 5;
        int row = g * 128 + w * 16 + lr;
        int k = kf * 32 + k8;
        v = (k < 128) ? Wih1[row * 128 + k] : Whh1[row * 128 + (k - 128)];
      } else if (idx < 196608) {              // WC2V: Wih2
        int f = frag - 256;
        int kf = f & 3, g = (f >> 2) & 3, w = f >> 4;
        v = Wih2[(g * 128 + w * 16 + lr) * 128 + kf * 32 + k8];
      } else if (idx < 262144) {              // WC2L: Whh2
        int f = frag - 384;
        int kf = f & 3, g = (f >> 2) & 3, w = f >> 4;
        v = Whh2[(g * 128 + w * 16 + lr) * 128 + kf * 32 + k8];
      } else if (idx < 278528) {              // W1
        int f = frag - 512; int kf = f & 1, n = f >> 1;
        v = W_in1[(n * 16 + lr) * 64 + kf * 32 + k8];
      } else if (idx < 311296) {              // W2
        int f = frag - 544; int kf = f & 7, n = f >> 3;
        v = W_in2[(n * 16 + lr) * 256 + kf * 32 + k8];
      } else if (idx < 327680) {              // W3
        int f = frag - 608; int kf = f & 3, n = f >> 2;
        v = W_in3[(n * 16 + lr) * 128 + kf * 32 + k8];
      } else if (idx < 344064) {              // WO1
        int f = frag - 640; int kf = f & 3, n = f >> 2;
        v = W_out1[(n * 16 + lr) * 128 + kf * 32 + k8];
      } else if (idx < 376832) {              // WO2
        int f = frag - 672; int kf = f & 3, n = f >> 2;
        v = W_out2[(n * 16 + lr) * 128 + kf * 32 + k8];
      } else {                                // WO3
        int f = frag - 736; int kf = f & 7, n = f >> 3;
        v = W_out3[(n * 16 + lr) * 256 + kf * 32 + k8];
      }
      wsu[idx] = f2bf(v);
    } else if (idx < 385536) {
      int i = idx - 385024; wsf[BS1_F + i] = bih1[i] + bhh1[i];
    } else if (idx < 386048) {
      int i = idx - 385536; wsf[BS2_F + i] = bih2[i] + bhh2[i];
    } else if (idx < 393216) {
      // pad
    } else if (idx < 917504) {
      int i = idx - 393216; wsu[STH1_U + i] = f2bf(h1_in[i]);
    } else if (idx < 1441792) {
      int i = idx - 917504; wsu[STH2_U + i] = f2bf(h2_in[i]);
    } else if (idx < 1966080) {
      int i = idx - 1441792; wsf[C1_F + i] = c1_in[i];
    } else {
      int i = idx - 1966080; wsf[C2_F + i] = c2_in[i];
    }
  }
}

// ======================= fc_in chunk =======================================
__global__ __launch_bounds__(256, 2)
void fc_chunk(const float* __restrict__ seq,
              const float* __restrict__ b_in1, const float* __restrict__ b_in2,
              const float* __restrict__ b_in3,
              u16* __restrict__ wsu, int t0) {
  __shared__ u16 SEQs[4096];
  __shared__ u16 F1s[16384];
  __shared__ u16 F2s[8192];
  const int tid = threadIdx.x;
  const int wid = tid >> 6, lane = tid & 63;
  const int lr = lane & 15, lg = lane >> 4;
  const int bid = blockIdx.x;

#pragma unroll
  for (int i = 0; i < 4; ++i) {
    int f = i * 1024 + tid * 4;
    int rho = f >> 6, k = f & 63;
    int b = bid * 2 + (rho >> 5), tl = rho & 31;
    float4 v = *(const float4*)(seq + ((size_t)b * 256 + t0 + tl) * 64 + k);
    u16x4 o = { f2bf(v.x), f2bf(v.y), f2bf(v.z), f2bf(v.w) };
    *(u16x4*)&SEQs[(rho * 64 + k) ^ ((rho & 7) << 3)] = o;
  }
  __syncthreads();

  {
    f32x4 a1[4][4] = {};
#pragma unroll
    for (int kf = 0; kf < 2; ++kf) {
      bf16x8 A[4];
#pragma unroll
      for (int rt = 0; rt < 4; ++rt) {
        int r = 16 * rt + lr;
        A[rt] = *(const bf16x8*)&SEQs[(r * 64 + (kf * 4 + lg) * 8) ^ ((r & 7) << 3)];
      }
#pragma unroll
      for (int n = 0; n < 4; ++n) {
        bf16x8 B = *(const bf16x8*)(wsu + W1_U + (size_t)(((4 * wid + n) * 2 + kf) * 512) + lane * 8);
#pragma unroll
        for (int rt = 0; rt < 4; ++rt) a1[rt][n] = MFMA16(A[rt], B, a1[rt][n]);
      }
    }
#pragma unroll
    for (int n = 0; n < 4; ++n) {
      float bb = b_in1[(4 * wid + n) * 16 + lr];
#pragma unroll
      for (int rt = 0; rt < 4; ++rt)
#pragma unroll
        for (int j = 0; j < 4; ++j) {
          int r = 16 * rt + lg * 4 + j, c = (4 * wid + n) * 16 + lr;
          F1s[(r * 256 + c) ^ ((r & 7) << 3)] = f2bf(fmaxf(a1[rt][n][j] + bb, 0.f));
        }
    }
  }
  __syncthreads();

  {
    f32x4 a2[4][2] = {};
#pragma unroll
    for (int kf = 0; kf < 8; ++kf) {
      bf16x8 A[4];
#pragma unroll
      for (int rt = 0; rt < 4; ++rt) {
        int r = 16 * rt + lr;
        A[rt] = *(const bf16x8*)&F1s[(r * 256 + (kf * 4 + lg) * 8) ^ ((r & 7) << 3)];
      }
#pragma unroll
      for (int n = 0; n < 2; ++n) {
        bf16x8 B = *(const bf16x8*)(wsu + W2_U + (size_t)(((2 * wid + n) * 8 + kf) * 512) + lane * 8);
#pragma unroll
        for (int rt = 0; rt < 4; ++rt) a2[rt][n] = MFMA16(A[rt], B, a2[rt][n]);
      }
    }
#pragma unroll
    for (int n = 0; n < 2; ++n) {
      float bb = b_in2[(2 * wid + n) * 16 + lr];
#pragma unroll
      for (int rt = 0; rt < 4; ++rt)
#pragma unroll
        for (int j = 0; j < 4; ++j) {
          int r = 16 * rt + lg * 4 + j, c = (2 * wid + n) * 16 + lr;
          F2s[(r * 128 + c) ^ ((r & 7) << 3)] = f2bf(fmaxf(a2[rt][n][j] + bb, 0.f));
        }
    }
  }
  __syncthreads();

  {
    f32x4 a3[4][2] = {};
#pragma unroll
    for (int kf = 0; kf < 4; ++kf) {
      bf16x8 A[4];
#pragma unroll
      for (int rt = 0; rt < 4; ++rt) {
        int r = 16 * rt + lr;
        A[rt] = *(const bf16x8*)&F2s[(r * 128 + (kf * 4 + lg) * 8) ^ ((r & 7) << 3)];
      }
#pragma unroll
      for (int n = 0; n < 2; ++n) {
        bf16x8 B = *(const bf16x8*)(wsu + W3_U + (size_t)(((2 * wid + n) * 4 + kf) * 512) + lane * 8);
#pragma unroll
        for (int rt = 0; rt < 4; ++rt) a3[rt][n] = MFMA16(A[rt], B, a3[rt][n]);
      }
    }
#pragma unroll
    for (int n = 0; n < 2; ++n) {
      float bb = b_in3[(2 * wid + n) * 16 + lr];
#pragma unroll
      for (int rt = 0; rt < 4; ++rt)
#pragma unroll
        for (int j = 0; j < 4; ++j) {
          int rho = 16 * rt + lg * 4 + j;
          int b = bid * 2 + (rho >> 5), tl = rho & 31;
          int c = (2 * wid + n) * 16 + lr;
          wsu[XB_U + ((size_t)tl * 4096 + b) * 128 + c] = f2bf(fmaxf(a3[rt][n][j] + bb, 0.f));
        }
    }
  }
}

// ======================= scan chunk ========================================
__global__ __launch_bounds__(512, 1)
void scan_chunk(u16* __restrict__ wsu, float* __restrict__ out,
                const float* __restrict__ b_out1, const float* __restrict__ b_out2,
                const float* __restrict__ b_out3, int last) {
  __shared__ u16 Wl[65536];                 // 128 KB: Whh2 B-frags
  __shared__ u16 XB[2][2048];               // x double buffer [16][128]
  __shared__ u16 H1b[2][2048], H2b[2][2048];

  float* wsf = (float*)wsu;
  const int tid = threadIdx.x;
  const int wid = tid >> 6, lane = tid & 63;
  const int lr = lane & 15, lg = lane >> 4;
  const int b0 = blockIdx.x * 16;
  const int r5 = tid >> 5, c5 = (tid & 31) * 4;
  const int swl = (r5 * 128 + c5) ^ ((r5 & 7) << 3);

  // ---- register-resident weights (pinned) ----
  bf16x8 wgt1[4][8], wgt2v[4][4];
#pragma unroll
  for (int g = 0; g < 4; ++g) {
#pragma unroll
    for (int kf = 0; kf < 8; ++kf)
      wgt1[g][kf] = *(const bf16x8*)(wsu + WC1_U + (size_t)(((wid * 4 + g) * 8 + kf) * 512) + lane * 8);
#pragma unroll
    for (int kf = 0; kf < 4; ++kf)
      wgt2v[g][kf] = *(const bf16x8*)(wsu + WC2V_U + (size_t)(((wid * 4 + g) * 4 + kf) * 512) + lane * 8);
  }
#pragma unroll
  for (int g = 0; g < 4; ++g) {
#pragma unroll
    for (int kf = 0; kf < 8; ++kf) asm volatile("" : "+v"(wgt1[g][kf]));
#pragma unroll
    for (int kf = 0; kf < 4; ++kf) asm volatile("" : "+v"(wgt2v[g][kf]));
  }

  // ---- Whh2 -> Wl LDS ----
#pragma unroll
  for (int i = 0; i < 16; ++i)
    GLOAD_LDS(wsu + WC2L_U + wid * 8192 + i * 512 + lane * 8, &Wl[wid * 8192 + i * 512]);

  // ---- stage state: H1b[0]=h1(-1), H2b[1]=h2(-1), XB[0]=x(0), XB[1]=x(1) --
  *(u16x4*)&H1b[0][swl] = *(const u16x4*)(wsu + STH1_U + (size_t)(b0 + r5) * 128 + c5);
  *(u16x4*)&H2b[1][swl] = *(const u16x4*)(wsu + STH2_U + (size_t)(b0 + r5) * 128 + c5);
  *(u16x4*)&XB[0][swl]  = *(const u16x4*)(wsu + XB_U + ((size_t)0 * 4096 + b0 + r5) * 128 + c5);
  *(u16x4*)&XB[1][swl]  = *(const u16x4*)(wsu + XB_U + ((size_t)1 * 4096 + b0 + r5) * 128 + c5);

  float cs1[4], cs2[4], bc1[4], bc2[4];
#pragma unroll
  for (int j = 0; j < 4; ++j) {
    cs1[j] = wsf[C1_F + (size_t)(b0 + lg * 4 + j) * 128 + 16 * wid + lr];
    cs2[j] = wsf[C2_F + (size_t)(b0 + lg * 4 + j) * 128 + 16 * wid + lr];
  }
#pragma unroll
  for (int g = 0; g < 4; ++g) {
    bc1[g] = wsf[BS1_F + g * 128 + 16 * wid + lr];
    bc2[g] = wsf[BS2_F + g * 128 + 16 * wid + lr];
  }
  __syncthreads();   // stage + Wl gload_lds drained (full vmcnt drain here)

  // ---- helpers ----
  auto frag = [&](const u16* buf, int kg) -> bf16x8 {
    return *(const bf16x8*)&buf[(lr * 128 + kg * 8) ^ ((lr & 7) << 3)];
  };
  auto ew = [&](f32x4 (&a)[4], float (&cs)[4], u16 (&hv)[4]) {
#pragma unroll
    for (int j = 0; j < 4; ++j) {
      float cn = fsig(a[1][j]) * cs[j] + fsig(a[0][j]) * ftanh(a[2][j]);
      cs[j] = cn;
      hv[j] = f2bf(fsig(a[3][j]) * ftanh(cn));
    }
  };
  auto hwrite = [&](u16* buf, const u16 (&hv)[4]) {
#pragma unroll
    for (int j = 0; j < 4; ++j) {
      int r = lg * 4 + j;
      buf[(r * 128 + 16 * wid + lr) ^ ((r & 7) << 3)] = hv[j];
    }
  };

  // ---- prologue: cell1(0) -> h1(0) into H1b[0] ----
  {
    f32x4 a1[4];
#pragma unroll
    for (int g = 0; g < 4; ++g) a1[g] = (f32x4){bc1[g], bc1[g], bc1[g], bc1[g]};
    bf16x8 h1f[4];
#pragma unroll
    for (int kf = 0; kf < 4; ++kf) h1f[kf] = frag(H1b[0], kf * 4 + lg);
#pragma unroll
    for (int kf = 0; kf < 4; ++kf) {
      bf16x8 xf = frag(XB[0], kf * 4 + lg);
#pragma unroll
      for (int g = 0; g < 4; ++g) a1[g] = MFMA16(xf, wgt1[g][kf], a1[g]);
    }
#pragma unroll
    for (int kf = 0; kf < 4; ++kf)
#pragma unroll
      for (int g = 0; g < 4; ++g) a1[g] = MFMA16(h1f[kf], wgt1[g][4 + kf], a1[g]);
    u16 hv[4];
    ew(a1, cs1, hv);
    LGKM_BAR;                 // all reads of H1b[0]/XB[0] done
    hwrite(H1b[0], hv);       // h1(0)
    LGKM_BAR;
  }

  // ================= main loop: iter i = {cell2(i), cell1(i+1)} ===========
  // reads:  H1b[p]=h1(i), H2b[q]=h2(i-1), XB[q]=x(i+1)
  // writes: H2b[p]=h2(i), H1b[q]=h1(i+1), XB[p]=x(i+2)   -> 1 barrier
#pragma unroll 2
  for (int tl = 0; tl < TC - 1; ++tl) {
    const int p = tl & 1, q = p ^ 1;
    int tn = tl + 2; if (tn > TC - 1) tn = TC - 1;
    u16x4 xn = *(const u16x4*)(wsu + XB_U + ((size_t)tn * 4096 + b0 + r5) * 128 + c5);

    bf16x8 h1f[4];
#pragma unroll
    for (int kf = 0; kf < 4; ++kf) h1f[kf] = frag(H1b[p], kf * 4 + lg);

    // ---- cell2(i) ----
    f32x4 a2[4];
#pragma unroll
    for (int g = 0; g < 4; ++g) a2[g] = (f32x4){bc2[g], bc2[g], bc2[g], bc2[g]};
#pragma unroll
    for (int kf = 0; kf < 4; ++kf)
#pragma unroll
      for (int g = 0; g < 4; ++g) a2[g] = MFMA16(h1f[kf], wgt2v[g][kf], a2[g]);
#pragma unroll
    for (int kf = 0; kf < 4; ++kf) {
      bf16x8 h2f = frag(H2b[q], kf * 4 + lg);
#pragma unroll
      for (int g = 0; g < 4; ++g) {
        bf16x8 B = *(const bf16x8*)&Wl[(((wid * 4 + g) * 4 + kf) * 512) + lane * 8];
        a2[g] = MFMA16(h2f, B, a2[g]);
      }
    }
    u16 hv[4];
    ew(a2, cs2, hv);
    hwrite(H2b[p], hv);       // h2(i)

    // ---- cell1(i+1) ----
    f32x4 a1[4];
#pragma unroll
    for (int g = 0; g < 4; ++g) a1[g] = (f32x4){bc1[g], bc1[g], bc1[g], bc1[g]};
#pragma unroll
    for (int kf = 0; kf < 4; ++kf) {
      bf16x8 xf = frag(XB[q], kf * 4 + lg);
#pragma unroll
      for (int g = 0; g < 4; ++g) a1[g] = MFMA16(xf, wgt1[g][kf], a1[g]);
    }
#pragma unroll
    for (int kf = 0; kf < 4; ++kf)
#pragma unroll
      for (int g = 0; g < 4; ++g) a1[g] = MFMA16(h1f[kf], wgt1[g][4 + kf], a1[g]);
    ew(a1, cs1, hv);
    hwrite(H1b[q], hv);       // h1(i+1)
    *(u16x4*)&XB[p][swl] = xn;  // x(i+2)
    LGKM_BAR;
  }

  // ---- epilogue: cell2(TC-1); h1(TC-1) in H1b[1], h2(TC-2) in H2b[0] ----
  {
    bf16x8 h1f[4];
#pragma unroll
    for (int kf = 0; kf < 4; ++kf) h1f[kf] = frag(H1b[1], kf * 4 + lg);
    f32x4 a2[4];
#pragma unroll
    for (int g = 0; g < 4; ++g) a2[g] = (f32x4){bc2[g], bc2[g], bc2[g], bc2[g]};
#pragma unroll
    for (int kf = 0; kf < 4; ++kf)
#pragma unroll
      for (int g = 0; g < 4; ++g) a2[g] = MFMA16(h1f[kf], wgt2v[g][kf], a2[g]);
#pragma unroll
    for (int kf = 0; kf < 4; ++kf) {
      bf16x8 h2f = frag(H2b[0], kf * 4 + lg);
#pragma unroll
      for (int g = 0; g < 4; ++g) {
        bf16x8 B = *(const bf16x8*)&Wl[(((wid * 4 + g) * 4 + kf) * 512) + lane * 8];
        a2[g] = MFMA16(h2f, B, a2[g]);
      }
    }
    u16 hv[4];
    ew(a2, cs2, hv);

    if (!last) {
      // ---- persist state ----
#pragma unroll
      for (int j = 0; j < 4; ++j)
        wsu[STH2_U + (size_t)(b0 + lg * 4 + j) * 128 + 16 * wid + lr] = hv[j];
      *(u16x4*)(wsu + STH1_U + (size_t)(b0 + r5) * 128 + c5) = *(const u16x4*)&H1b[1][swl];
#pragma unroll
      for (int j = 0; j < 4; ++j) {
        wsf[C1_F + (size_t)(b0 + lg * 4 + j) * 128 + 16 * wid + lr] = cs1[j];
        wsf[C2_F + (size_t)(b0 + lg * 4 + j) * 128 + 16 * wid + lr] = cs2[j];
      }
    } else {
      hwrite(H2b[1], hv);     // h2(255) for the head
      LGKM_BAR;
      // ---- head: Y1 -> XB[0], Y2 -> XB[0]|H1b[0], Y3 -> out ----
      {
        f32x4 y1 = {};
#pragma unroll
        for (int kf = 0; kf < 4; ++kf) {
          bf16x8 A = frag(H2b[1], kf * 4 + lg);
          bf16x8 B = *(const bf16x8*)(wsu + WO1_U + (size_t)((wid * 4 + kf) * 512) + lane * 8);
          y1 = MFMA16(A, B, y1);
        }
        float bo1 = b_out1[wid * 16 + lr];
        LGKM_BAR;
#pragma unroll
        for (int j = 0; j < 4; ++j) {
          int r = lg * 4 + j;
          XB[0][(r * 128 + 16 * wid + lr) ^ ((r & 7) << 3)] = f2bf(fmaxf(y1[j] + bo1, 0.f));
        }
        LGKM_BAR;
      }
      {
        f32x4 y2[2] = {};
#pragma unroll
        for (int kf = 0; kf < 4; ++kf) {
          bf16x8 A = frag(XB[0], kf * 4 + lg);
#pragma unroll
          for (int n = 0; n < 2; ++n) {
            bf16x8 B = *(const bf16x8*)(wsu + WO2_U + (size_t)(((2 * wid + n) * 4 + kf) * 512) + lane * 8);
            y2[n] = MFMA16(A, B, y2[n]);
          }
        }
        LGKM_BAR;    // Y1 reads done before overwrite
#pragma unroll
        for (int n = 0; n < 2; ++n)
#pragma unroll
          for (int j = 0; j < 4; ++j) {
            int c = (2 * wid + n) * 16 + lr;
            float v = fmaxf(y2[n][j] + b_out2[c], 0.f);
            u16* buf = (c < 128) ? &XB[0][0] : &H1b[0][0];
            int cc = c & 127, r = lg * 4 + j;
            buf[(r * 128 + cc) ^ ((r & 7) << 3)] = f2bf(v);
          }
        LGKM_BAR;
      }
      if (wid < 2) {
        f32x4 y3 = {};
#pragma unroll
        for (int kf = 0; kf < 8; ++kf) {
          const u16* ab = (kf < 4) ? &XB[0][0] : &H1b[0][0];
          bf16x8 A = frag(ab, (kf & 3) * 4 + lg);
          bf16x8 B = *(const bf16x8*)(wsu + WO3_U + (size_t)((wid * 8 + kf) * 512) + lane * 8);
          y3 = MFMA16(A, B, y3);
        }
        float bo3 = b_out3[wid * 16 + lr];
#pragma unroll
        for (int j = 0; j < 4; ++j)
          out[(size_t)(b0 + lg * 4 + j) * 32 + wid * 16 + lr] = y3[j] + bo3;
      }
    }
  }
}

// ======================= host ==============================================
extern "C" void kernel_launch(void* const* d_in, const int* in_sizes, int n_in,
                              void* d_out, int out_size, void* d_ws, size_t ws_size,
                              hipStream_t stream) {
  (void)in_sizes; (void)n_in; (void)out_size; (void)ws_size;
  const float* seq    = (const float*)d_in[0];
  const float* h1     = (const float*)d_in[1];
  const float* c1     = (const float*)d_in[2];
  const float* h2     = (const float*)d_in[3];
  const float* c2     = (const float*)d_in[4];
  const float* W_in1  = (const float*)d_in[5];
  const float* b_in1  = (const float*)d_in[6];
  const float* W_in2  = (const float*)d_in[7];
  const float* b_in2  = (const float*)d_in[8];
  const float* W_in3  = (const float*)d_in[9];
  const float* b_in3  = (const float*)d_in[10];
  const float* Wih1   = (const float*)d_in[11];
  const float* Whh1   = (const float*)d_in[12];
  const float* bih1   = (const float*)d_in[13];
  const float* bhh1   = (const float*)d_in[14];
  const float* Wih2   = (const float*)d_in[15];
  const float* Whh2   = (const float*)d_in[16];
  const float* bih2   = (const float*)d_in[17];
  const float* bhh2   = (const float*)d_in[18];
  const float* W_out1 = (const float*)d_in[19];
  const float* b_out1 = (const float*)d_in[20];
  const float* W_out2 = (const float*)d_in[21];
  const float* b_out2 = (const float*)d_in[22];
  const float* W_out3 = (const float*)d_in[23];
  const float* b_out3 = (const float*)d_in[24];
  u16* wsu = (u16*)d_ws;
  float* out = (float*)d_out;

  hipLaunchKernelGGL(prep_kernel, dim3(512), dim3(256), 0, stream,
                     Wih1, Whh1, bih1, bhh1, Wih2, Whh2, bih2, bhh2,
                     W_in1, W_in2, W_in3, W_out1, W_out2, W_out3,
                     h1, h2, c1, c2, wsu);
  for (int k = 0; k < NCH; ++k) {
    hipLaunchKernelGGL(fc_chunk, dim3(2048), dim3(256), 0, stream,
                       seq, b_in1, b_in2, b_in3, wsu, k * TC);
    hipLaunchKernelGGL(scan_chunk, dim3(256), dim3(512), 0, stream,
                       wsu, out, b_out1, b_out2, b_out3, (k == NCH - 1) ? 1 : 0);
  }
}

// Round 8
// 1924.293 us; speedup vs baseline: 1.0892x; 1.0892x over previous
//
#include <hip/hip_runtime.h>

// ---------------------------------------------------------------------------
// R8: spill-free resident-weight scan + g1x precompute.
//  - fc_chunk: x = fc_in(seq) AND g1x = x@Wih1^T + bs1 for a 32-step chunk,
//    stored bf16 in scan-fragment order (both sides 128B-coalesced).
//  - scan_chunk: 256 blocks x 512 thr, 16 batch rows. Weights: Whh1+Wih2 in
//    128 VGPRs pinned "+a" (accum side), Whh2 in LDS (128KB). cell1 C-init
//    comes from g1x (bias folded) -> no x buffer, no bc1. 1 lgkm barrier/step.
//    Arch-side live set ~90 regs <= 128 => no scratch spill (R5-R7 bug).
//  ws: 8MB meta + 134MB g1x = ~143MB.
// ---------------------------------------------------------------------------

typedef unsigned short u16;
typedef short bf16x8 __attribute__((ext_vector_type(8)));
typedef float f32x4 __attribute__((ext_vector_type(4)));
typedef unsigned short u16x4 __attribute__((ext_vector_type(4)));

#define MFMA16(a, b, c) __builtin_amdgcn_mfma_f32_16x16x32_bf16((a), (b), (c), 0, 0, 0)

#define GLOAD_LDS(gp, lp) __builtin_amdgcn_global_load_lds( \
    (const __attribute__((address_space(1))) unsigned int*)(const void*)(gp), \
    (__attribute__((address_space(3))) unsigned int*)(void*)(lp), 16, 0, 0)

#define LGKM_BAR do { \
  asm volatile("s_waitcnt lgkmcnt(0)" ::: "memory"); \
  __builtin_amdgcn_sched_barrier(0); \
  __builtin_amdgcn_s_barrier(); \
  __builtin_amdgcn_sched_barrier(0); \
} while (0)

__device__ __forceinline__ u16 f2bf(float f) {
  union { float f; unsigned u; } v; v.f = f;
  return (u16)((v.u + 0x7FFFu + ((v.u >> 16) & 1u)) >> 16);  // RNE
}
__device__ __forceinline__ float b2f(u16 v) {
  union { unsigned u; float f; } x; x.u = ((unsigned)v) << 16; return x.f;
}
__device__ __forceinline__ float fsig(float x) { return 1.0f / (1.0f + __expf(-x)); }
__device__ __forceinline__ float ftanh(float x) { return 2.0f / (1.0f + __expf(-2.0f * x)) - 1.0f; }

// ---- ws layout (u16 / f32 indices) ---------------------------------------
#define WHH1_U  0         // 128 frags ((w*4+g)*4+kf)*512 : Whh1
#define WIH2_U  65536     // 128 frags : Wih2
#define WHH2_U  131072    // 128 frags (w*16+g*4+kf)*512 : Whh2 (LDS image)
#define WIH1_U  196608    // 128 frags (n*4+kf)*512, n=0..31 : Wih1 (fc L4)
#define W1_U    262144    // 32 frags (n*2+kf)
#define W2_U    278528    // 64 frags (n*8+kf)
#define W3_U    311296    // 32 frags (n*4+kf)
#define WO1_U   327680    // 32 frags
#define WO2_U   344064    // 64 frags
#define WO3_U   376832    // 16 frags
#define BS1_F   192512    // f32[512] = bih1+bhh1 (folded into g1x)
#define BS2_F   193024    // f32[512] = bih2+bhh2
#define STH1_U  393216    // bf16[4096*128]
#define STH2_U  917504
#define C1_F    720896    // f32[4096*128]
#define C2_F    1245184
#define G1X_U   4194304   // bf16 g1x chunk buffer @ byte 8388608, 134MB
#define TC      32
#define NCH     8

// g1x u16 index: (((((tl*256+blk)*4+slg)*4+g)*8+swid)*16+slr)*4 + sj
//   b = blk*16 + slg*4 + sj ; c = g*128 + swid*16 + slr

// ======================= prep ==============================================
__global__ void prep_kernel(const float* __restrict__ Wih1, const float* __restrict__ Whh1,
                            const float* __restrict__ bih1, const float* __restrict__ bhh1,
                            const float* __restrict__ Wih2, const float* __restrict__ Whh2,
                            const float* __restrict__ bih2, const float* __restrict__ bhh2,
                            const float* __restrict__ W_in1, const float* __restrict__ W_in2,
                            const float* __restrict__ W_in3,
                            const float* __restrict__ W_out1, const float* __restrict__ W_out2,
                            const float* __restrict__ W_out3,
                            const float* __restrict__ h1_in, const float* __restrict__ h2_in,
                            const float* __restrict__ c1_in, const float* __restrict__ c2_in,
                            u16* __restrict__ wsu) {
  float* wsf = (float*)wsu;
  const int N_total = 2490368;
  int stride = gridDim.x * blockDim.x;
  for (int idx = blockIdx.x * blockDim.x + threadIdx.x; idx < N_total; idx += stride) {
    if (idx < 385024) {
      int within = idx & 511;
      int f = idx >> 9;                       // global frag
      int lane = within >> 3, e = within & 7;
      int lr = lane & 15, lg = lane >> 4;
      int k8 = lg * 8 + e;
      float v;
      if (f < 128) {                          // WHH1
        int kf = f & 3, g = (f >> 2) & 3, w = f >> 4;
        v = Whh1[(g * 128 + w * 16 + lr) * 128 + kf * 32 + k8];
      } else if (f < 256) {                   // WIH2
        int ff = f - 128; int kf = ff & 3, g = (ff >> 2) & 3, w = ff >> 4;
        v = Wih2[(g * 128 + w * 16 + lr) * 128 + kf * 32 + k8];
      } else if (f < 384) {                   // WHH2
        int ff = f - 256; int kf = ff & 3, g = (ff >> 2) & 3, w = ff >> 4;
        v = Whh2[(g * 128 + w * 16 + lr) * 128 + kf * 32 + k8];
      } else if (f < 512) {                   // WIH1 (fc L4)
        int ff = f - 384; int kf = ff & 3, n = ff >> 2;
        v = Wih1[(n * 16 + lr) * 128 + kf * 32 + k8];
      } else if (f < 544) {                   // W1
        int ff = f - 512; int kf = ff & 1, n = ff >> 1;
        v = W_in1[(n * 16 + lr) * 64 + kf * 32 + k8];
      } else if (f < 608) {                   // W2
        int ff = f - 544; int kf = ff & 7, n = ff >> 3;
        v = W_in2[(n * 16 + lr) * 256 + kf * 32 + k8];
      } else if (f < 640) {                   // W3
        int ff = f - 608; int kf = ff & 3, n = ff >> 2;
        v = W_in3[(n * 16 + lr) * 128 + kf * 32 + k8];
      } else if (f < 672) {                   // WO1
        int ff = f - 640; int kf = ff & 3, n = ff >> 2;
        v = W_out1[(n * 16 + lr) * 128 + kf * 32 + k8];
      } else if (f < 736) {                   // WO2
        int ff = f - 672; int kf = ff & 3, n = ff >> 2;
        v = W_out2[(n * 16 + lr) * 128 + kf * 32 + k8];
      } else {                                // WO3
        int ff = f - 736; int kf = ff & 7, n = ff >> 3;
        v = W_out3[(n * 16 + lr) * 256 + kf * 32 + k8];
      }
      wsu[idx] = f2bf(v);
    } else if (idx < 385536) {
      int i = idx - 385024; wsf[BS1_F + i] = bih1[i] + bhh1[i];
    } else if (idx < 386048) {
      int i = idx - 385536; wsf[BS2_F + i] = bih2[i] + bhh2[i];
    } else if (idx < 393216) {
      // pad
    } else if (idx < 917504) {
      int i = idx - 393216; wsu[STH1_U + i] = f2bf(h1_in[i]);
    } else if (idx < 1441792) {
      int i = idx - 917504; wsu[STH2_U + i] = f2bf(h2_in[i]);
    } else if (idx < 1966080) {
      int i = idx - 1441792; wsf[C1_F + i] = c1_in[i];
    } else {
      int i = idx - 1966080; wsf[C2_F + i] = c2_in[i];
    }
  }
}

// ======================= fc chunk ==========================================
// 2048 blocks (1024 b-groups x 2 t-halves) x 256 thr; block = 4 b x 16 t.
__global__ __launch_bounds__(256, 2)
void fc_chunk(const float* __restrict__ seq,
              const float* __restrict__ b_in1, const float* __restrict__ b_in2,
              const float* __restrict__ b_in3,
              u16* __restrict__ wsu, int t0) {
  __shared__ u16 SEQs[4096];   // [64][64]
  __shared__ u16 F1s[16384];   // [64][256]
  __shared__ u16 F2s[8192];    // [64][128]
  __shared__ u16 XLs[8192];    // [64][128] (L3 out)
  const int tid = threadIdx.x;
  const int wid = tid >> 6, lane = tid & 63;
  const int lr = lane & 15, lg = lane >> 4;
  const int bid_t = blockIdx.x & 1, bid_b = blockIdx.x >> 1;
  const int b0c = bid_b * 4, t0c = t0 + bid_t * 16;
  const float* bs1f = (const float*)wsu + BS1_F;

  // stage seq rows rho=(b_local*16+t_local), f32 -> bf16 swizzled
#pragma unroll
  for (int i = 0; i < 4; ++i) {
    int f = i * 1024 + tid * 4;
    int rho = f >> 6, k = f & 63;
    int b = b0c + (rho >> 4), tt = t0c + (rho & 15);
    float4 v = *(const float4*)(seq + ((size_t)b * 256 + tt) * 64 + k);
    u16x4 o = { f2bf(v.x), f2bf(v.y), f2bf(v.z), f2bf(v.w) };
    *(u16x4*)&SEQs[(rho * 64 + k) ^ ((rho & 7) << 3)] = o;
  }
  __syncthreads();

  { // L1: [64,256], K=64
    f32x4 a1[4][4] = {};
#pragma unroll
    for (int kf = 0; kf < 2; ++kf) {
      bf16x8 A[4];
#pragma unroll
      for (int rt = 0; rt < 4; ++rt) {
        int r = 16 * rt + lr;
        A[rt] = *(const bf16x8*)&SEQs[(r * 64 + (kf * 4 + lg) * 8) ^ ((r & 7) << 3)];
      }
#pragma unroll
      for (int n = 0; n < 4; ++n) {
        bf16x8 B = *(const bf16x8*)(wsu + W1_U + (size_t)(((4 * wid + n) * 2 + kf) * 512) + lane * 8);
#pragma unroll
        for (int rt = 0; rt < 4; ++rt) a1[rt][n] = MFMA16(A[rt], B, a1[rt][n]);
      }
    }
#pragma unroll
    for (int n = 0; n < 4; ++n) {
      float bb = b_in1[(4 * wid + n) * 16 + lr];
#pragma unroll
      for (int rt = 0; rt < 4; ++rt)
#pragma unroll
        for (int j = 0; j < 4; ++j) {
          int r = 16 * rt + lg * 4 + j, c = (4 * wid + n) * 16 + lr;
          F1s[(r * 256 + c) ^ ((r & 7) << 3)] = f2bf(fmaxf(a1[rt][n][j] + bb, 0.f));
        }
    }
  }
  __syncthreads();

  { // L2: [64,128], K=256
    f32x4 a2[4][2] = {};
#pragma unroll
    for (int kf = 0; kf < 8; ++kf) {
      bf16x8 A[4];
#pragma unroll
      for (int rt = 0; rt < 4; ++rt) {
        int r = 16 * rt + lr;
        A[rt] = *(const bf16x8*)&F1s[(r * 256 + (kf * 4 + lg) * 8) ^ ((r & 7) << 3)];
      }
#pragma unroll
      for (int n = 0; n < 2; ++n) {
        bf16x8 B = *(const bf16x8*)(wsu + W2_U + (size_t)(((2 * wid + n) * 8 + kf) * 512) + lane * 8);
#pragma unroll
        for (int rt = 0; rt < 4; ++rt) a2[rt][n] = MFMA16(A[rt], B, a2[rt][n]);
      }
    }
#pragma unroll
    for (int n = 0; n < 2; ++n) {
      float bb = b_in2[(2 * wid + n) * 16 + lr];
#pragma unroll
      for (int rt = 0; rt < 4; ++rt)
#pragma unroll
        for (int j = 0; j < 4; ++j) {
          int r = 16 * rt + lg * 4 + j, c = (2 * wid + n) * 16 + lr;
          F2s[(r * 128 + c) ^ ((r & 7) << 3)] = f2bf(fmaxf(a2[rt][n][j] + bb, 0.f));
        }
    }
  }
  __syncthreads();

  { // L3: [64,128], K=128 -> XLs
    f32x4 a3[4][2] = {};
#pragma unroll
    for (int kf = 0; kf < 4; ++kf) {
      bf16x8 A[4];
#pragma unroll
      for (int rt = 0; rt < 4; ++rt) {
        int r = 16 * rt + lr;
        A[rt] = *(const bf16x8*)&F2s[(r * 128 + (kf * 4 + lg) * 8) ^ ((r & 7) << 3)];
      }
#pragma unroll
      for (int n = 0; n < 2; ++n) {
        bf16x8 B = *(const bf16x8*)(wsu + W3_U + (size_t)(((2 * wid + n) * 4 + kf) * 512) + lane * 8);
#pragma unroll
        for (int rt = 0; rt < 4; ++rt) a3[rt][n] = MFMA16(A[rt], B, a3[rt][n]);
      }
    }
#pragma unroll
    for (int n = 0; n < 2; ++n) {
      float bb = b_in3[(2 * wid + n) * 16 + lr];
#pragma unroll
      for (int rt = 0; rt < 4; ++rt)
#pragma unroll
        for (int j = 0; j < 4; ++j) {
          int r = 16 * rt + lg * 4 + j, c = (2 * wid + n) * 16 + lr;
          XLs[(r * 128 + c) ^ ((r & 7) << 3)] = f2bf(fmaxf(a3[rt][n][j] + bb, 0.f));
        }
    }
  }
  __syncthreads();

  { // L4: g1x = x @ Wih1^T + bs1 : [64,512], K=128 -> global (fragment order)
    f32x4 a4[4][8] = {};
#pragma unroll
    for (int kf = 0; kf < 4; ++kf) {
      bf16x8 A[4];
#pragma unroll
      for (int rt = 0; rt < 4; ++rt) {
        int r = 16 * rt + lr;
        A[rt] = *(const bf16x8*)&XLs[(r * 128 + (kf * 4 + lg) * 8) ^ ((r & 7) << 3)];
      }
#pragma unroll
      for (int n = 0; n < 8; ++n) {
        bf16x8 B = *(const bf16x8*)(wsu + WIH1_U + (size_t)(((wid * 8 + n) * 4 + kf) * 512) + lane * 8);
#pragma unroll
        for (int rt = 0; rt < 4; ++rt) a4[rt][n] = MFMA16(A[rt], B, a4[rt][n]);
      }
    }
    // store: value(rt,n,j) -> b=b0c+rt (sj=rt), c=(wid*8+n)*16+lr (g=wid,
    // swid=n, slr=lr), tl=bid_t*16+lg*4+j. u16x4 packs sj contiguous.
    const int blk = bid_b >> 2, slg = bid_b & 3;
#pragma unroll
    for (int n = 0; n < 8; ++n) {
      float bb = bs1f[(wid * 8 + n) * 16 + lr];
#pragma unroll
      for (int j = 0; j < 4; ++j) {
        int tl = bid_t * 16 + lg * 4 + j;
        u16x4 o = { f2bf(a4[0][n][j] + bb), f2bf(a4[1][n][j] + bb),
                    f2bf(a4[2][n][j] + bb), f2bf(a4[3][n][j] + bb) };
        size_t au = (size_t)G1X_U +
            ((((((size_t)tl * 256 + blk) * 4 + slg) * 4 + wid) * 8 + n) * 16 + lr) * 4;
        *(u16x4*)(wsu + au) = o;
      }
    }
  }
}

// ======================= scan chunk ========================================
__global__ __launch_bounds__(512, 1)
void scan_chunk(u16* __restrict__ wsu, float* __restrict__ out,
                const float* __restrict__ b_out1, const float* __restrict__ b_out2,
                const float* __restrict__ b_out3, int last) {
  __shared__ u16 Wl[65536];                   // 128 KB Whh2 B-frags
  __shared__ u16 H1d[2][2048], H2d[2][2048];  // 16 KB

  float* wsf = (float*)wsu;
  const int tid = threadIdx.x;
  const int wid = tid >> 6, lane = tid & 63;
  const int lr = lane & 15, lg = lane >> 4;
  const int b0 = blockIdx.x * 16;
  const int blkid = blockIdx.x;
  const int r5 = tid >> 5, c5 = (tid & 31) * 4;
  const int swl = (r5 * 128 + c5) ^ ((r5 & 7) << 3);

  // ---- register weights -> pinned to AGPR side ("+a") ----
  bf16x8 wA[4][4], wB[4][4];   // Whh1, Wih2
#pragma unroll
  for (int g = 0; g < 4; ++g)
#pragma unroll
    for (int kf = 0; kf < 4; ++kf) {
      wA[g][kf] = *(const bf16x8*)(wsu + WHH1_U + (size_t)(((wid * 4 + g) * 4 + kf) * 512) + lane * 8);
      wB[g][kf] = *(const bf16x8*)(wsu + WIH2_U + (size_t)(((wid * 4 + g) * 4 + kf) * 512) + lane * 8);
    }
#pragma unroll
  for (int g = 0; g < 4; ++g)
#pragma unroll
    for (int kf = 0; kf < 4; ++kf) {
      asm volatile("" : "+a"(wA[g][kf]));
      asm volatile("" : "+a"(wB[g][kf]));
    }

  // ---- Whh2 -> Wl ----
#pragma unroll
  for (int i = 0; i < 16; ++i)
    GLOAD_LDS(wsu + WHH2_U + wid * 8192 + i * 512 + lane * 8, &Wl[wid * 8192 + i * 512]);

  // ---- state ----
  *(u16x4*)&H1d[0][swl] = *(const u16x4*)(wsu + STH1_U + (size_t)(b0 + r5) * 128 + c5);
  *(u16x4*)&H2d[0][swl] = *(const u16x4*)(wsu + STH2_U + (size_t)(b0 + r5) * 128 + c5);
  float cs1[4], cs2[4], bc2[4];
#pragma unroll
  for (int j = 0; j < 4; ++j) {
    cs1[j] = wsf[C1_F + (size_t)(b0 + lg * 4 + j) * 128 + 16 * wid + lr];
    cs2[j] = wsf[C2_F + (size_t)(b0 + lg * 4 + j) * 128 + 16 * wid + lr];
  }
#pragma unroll
  for (int g = 0; g < 4; ++g) bc2[g] = wsf[BS2_F + g * 128 + 16 * wid + lr];

  // ---- g1x(0) prefetch ----
  u16x4 gx[4];
#pragma unroll
  for (int g = 0; g < 4; ++g)
    gx[g] = *(const u16x4*)(wsu + G1X_U +
        ((((((size_t)0 * 256 + blkid) * 4 + lg) * 4 + g) * 8 + wid) * 16 + lr) * 4);

  __syncthreads();   // staging + Wl drained

  auto frag = [&](const u16* buf, int kg) -> bf16x8 {
    return *(const bf16x8*)&buf[(lr * 128 + kg * 8) ^ ((lr & 7) << 3)];
  };

  // ================= 32-step scan, 1 barrier/step =================
#pragma unroll 2
  for (int tl = 0; tl < TC; ++tl) {
    const int p = tl & 1, q = p ^ 1;

    // -- phase 1: cell1 = g1x(t) + Whh1 * h1(t-1) --
    f32x4 acc[4];
#pragma unroll
    for (int g = 0; g < 4; ++g)
      acc[g] = (f32x4){ b2f(gx[g][0]), b2f(gx[g][1]), b2f(gx[g][2]), b2f(gx[g][3]) };
    // prefetch g1x(t+1) immediately (full-step latency window)
    if (tl < TC - 1) {
#pragma unroll
      for (int g = 0; g < 4; ++g)
        gx[g] = *(const u16x4*)(wsu + G1X_U +
            ((((((size_t)(tl + 1) * 256 + blkid) * 4 + lg) * 4 + g) * 8 + wid) * 16 + lr) * 4);
    }
    bf16x8 h1f[4];
#pragma unroll
    for (int kf = 0; kf < 4; ++kf) h1f[kf] = frag(H1d[p], kf * 4 + lg);
#pragma unroll
    for (int kf = 0; kf < 4; ++kf)
#pragma unroll
      for (int g = 0; g < 4; ++g) acc[g] = MFMA16(h1f[kf], wA[g][kf], acc[g]);
    u16 hv[4];
#pragma unroll
    for (int j = 0; j < 4; ++j) {
      float cn = fsig(acc[1][j]) * cs1[j] + fsig(acc[0][j]) * ftanh(acc[2][j]);
      cs1[j] = cn;
      hv[j] = f2bf(fsig(acc[3][j]) * ftanh(cn));
    }
#pragma unroll
    for (int j = 0; j < 4; ++j) {
      int r = lg * 4 + j;
      H1d[q][(r * 128 + 16 * wid + lr) ^ ((r & 7) << 3)] = hv[j];
    }
    LGKM_BAR;   // h1(t) visible; all reads of H1d[p] complete

    // -- phase 2: cell2 = bs2 + Wih2 * h1(t) + Whh2 * h2(t-1) --
    f32x4 acd[4];
#pragma unroll
    for (int g = 0; g < 4; ++g) acd[g] = (f32x4){ bc2[g], bc2[g], bc2[g], bc2[g] };
#pragma unroll
    for (int kf = 0; kf < 4; ++kf) {
      bf16x8 h1n = frag(H1d[q], kf * 4 + lg);
#pragma unroll
      for (int g = 0; g < 4; ++g) acd[g] = MFMA16(h1n, wB[g][kf], acd[g]);
    }
#pragma unroll
    for (int kf = 0; kf < 4; ++kf) {
      bf16x8 h2f = frag(H2d[p], kf * 4 + lg);
#pragma unroll
      for (int g = 0; g < 4; ++g) {
        bf16x8 B = *(const bf16x8*)&Wl[((wid * 16 + g * 4 + kf) * 512) + lane * 8];
        acd[g] = MFMA16(h2f, B, acd[g]);
      }
    }
#pragma unroll
    for (int j = 0; j < 4; ++j) {
      float cn = fsig(acd[1][j]) * cs2[j] + fsig(acd[0][j]) * ftanh(acd[2][j]);
      cs2[j] = cn;
      hv[j] = f2bf(fsig(acd[3][j]) * ftanh(cn));
    }
#pragma unroll
    for (int j = 0; j < 4; ++j) {
      int r = lg * 4 + j;
      H2d[q][(r * 128 + 16 * wid + lr) ^ ((r & 7) << 3)] = hv[j];
    }
    // no barrier: next phase1 only reads H1d[q] (1 barrier old) and writes
    // H1d[p] (all reads of it completed before this iter's LGKM_BAR); the
    // next phase2's H2d[q] read is ordered by next iter's LGKM_BAR.
  }
  // TC even -> final h in H1d[0]/H2d[0] (needs one bar for visibility)
  LGKM_BAR;

  if (!last) {
    *(u16x4*)(wsu + STH1_U + (size_t)(b0 + r5) * 128 + c5) = *(const u16x4*)&H1d[0][swl];
    *(u16x4*)(wsu + STH2_U + (size_t)(b0 + r5) * 128 + c5) = *(const u16x4*)&H2d[0][swl];
#pragma unroll
    for (int j = 0; j < 4; ++j) {
      wsf[C1_F + (size_t)(b0 + lg * 4 + j) * 128 + 16 * wid + lr] = cs1[j];
      wsf[C2_F + (size_t)(b0 + lg * 4 + j) * 128 + 16 * wid + lr] = cs2[j];
    }
  } else {
    // ---- head: Y1 -> H1d[1]; Y2 -> H2d[1] (lo) | H1d[0] (hi); Y3 -> out ----
    {
      f32x4 y1 = {};
#pragma unroll
      for (int kf = 0; kf < 4; ++kf) {
        bf16x8 A = frag(H2d[0], kf * 4 + lg);
        bf16x8 B = *(const bf16x8*)(wsu + WO1_U + (size_t)((wid * 4 + kf) * 512) + lane * 8);
        y1 = MFMA16(A, B, y1);
      }
      float bo1 = b_out1[wid * 16 + lr];
      LGKM_BAR;
#pragma unroll
      for (int j = 0; j < 4; ++j) {
        int r = lg * 4 + j;
        H1d[1][(r * 128 + 16 * wid + lr) ^ ((r & 7) << 3)] = f2bf(fmaxf(y1[j] + bo1, 0.f));
      }
      LGKM_BAR;
    }
    {
      f32x4 y2[2] = {};
#pragma unroll
      for (int kf = 0; kf < 4; ++kf) {
        bf16x8 A = frag(H1d[1], kf * 4 + lg);
#pragma unroll
        for (int n = 0; n < 2; ++n) {
          bf16x8 B = *(const bf16x8*)(wsu + WO2_U + (size_t)(((2 * wid + n) * 4 + kf) * 512) + lane * 8);
          y2[n] = MFMA16(A, B, y2[n]);
        }
      }
      LGKM_BAR;
#pragma unroll
      for (int n = 0; n < 2; ++n)
#pragma unroll
        for (int j = 0; j < 4; ++j) {
          int c = (2 * wid + n) * 16 + lr;
          float v = fmaxf(y2[n][j] + b_out2[c], 0.f);
          u16* buf = (c < 128) ? &H2d[1][0] : &H1d[0][0];
          int cc = c & 127, r = lg * 4 + j;
          buf[(r * 128 + cc) ^ ((r & 7) << 3)] = f2bf(v);
        }
      LGKM_BAR;
    }
    if (wid < 2) {
      f32x4 y3 = {};
#pragma unroll
      for (int kf = 0; kf < 8; ++kf) {
        const u16* ab = (kf < 4) ? &H2d[1][0] : &H1d[0][0];
        bf16x8 A = frag(ab, (kf & 3) * 4 + lg);
        bf16x8 B = *(const bf16x8*)(wsu + WO3_U + (size_t)((wid * 8 + kf) * 512) + lane * 8);
        y3 = MFMA16(A, B, y3);
      }
      float bo3 = b_out3[wid * 16 + lr];
#pragma unroll
      for (int j = 0; j < 4; ++j)
        out[(size_t)(b0 + lg * 4 + j) * 32 + wid * 16 + lr] = y3[j] + bo3;
    }
  }
}

// ======================= host ==============================================
extern "C" void kernel_launch(void* const* d_in, const int* in_sizes, int n_in,
                              void* d_out, int out_size, void* d_ws, size_t ws_size,
                              hipStream_t stream) {
  (void)in_sizes; (void)n_in; (void)out_size; (void)ws_size;
  const float* seq    = (const float*)d_in[0];
  const float* h1     = (const float*)d_in[1];
  const float* c1     = (const float*)d_in[2];
  const float* h2     = (const float*)d_in[3];
  const float* c2     = (const float*)d_in[4];
  const float* W_in1  = (const float*)d_in[5];
  const float* b_in1  = (const float*)d_in[6];
  const float* W_in2  = (const float*)d_in[7];
  const float* b_in2  = (const float*)d_in[8];
  const float* W_in3  = (const float*)d_in[9];
  const float* b_in3  = (const float*)d_in[10];
  const float* Wih1   = (const float*)d_in[11];
  const float* Whh1   = (const float*)d_in[12];
  const float* bih1   = (const float*)d_in[13];
  const float* bhh1   = (const float*)d_in[14];
  const float* Wih2   = (const float*)d_in[15];
  const float* Whh2   = (const float*)d_in[16];
  const float* bih2   = (const float*)d_in[17];
  const float* bhh2   = (const float*)d_in[18];
  const float* W_out1 = (const float*)d_in[19];
  const float* b_out1 = (const float*)d_in[20];
  const float* W_out2 = (const float*)d_in[21];
  const float* b_out2 = (const float*)d_in[22];
  const float* W_out3 = (const float*)d_in[23];
  const float* b_out3 = (const float*)d_in[24];
  u16* wsu = (u16*)d_ws;
  float* out = (float*)d_out;

  hipLaunchKernelGGL(prep_kernel, dim3(512), dim3(256), 0, stream,
                     Wih1, Whh1, bih1, bhh1, Wih2, Whh2, bih2, bhh2,
                     W_in1, W_in2, W_in3, W_out1, W_out2, W_out3,
                     h1, h2, c1, c2, wsu);
  for (int k = 0; k < NCH; ++k) {
    hipLaunchKernelGGL(fc_chunk, dim3(2048), dim3(256), 0, stream,
                       seq, b_in1, b_in2, b_in3, wsu, k * TC);
    hipLaunchKernelGGL(scan_chunk, dim3(256), dim3(512), 0, stream,
                       wsu, out, b_out1, b_out2, b_out3, (k == NCH - 1) ? 1 : 0);
  }
}

// Round 9
// 1907.893 us; speedup vs baseline: 1.0986x; 1.0086x over previous
//
#include <hip/hip_runtime.h>

// ---------------------------------------------------------------------------
// R9: x-materialization (not g1x) + 2-launch scan with 3-matrix register
// residency.
//  - fc_all: x = fc_in(seq) for a TC-step chunk, bf16, [tl][4096][128],
//    coalesced store via LDS staging.
//  - scan: 256 blocks x 512 thr, 16 batch rows, TC steps. Registers (pinned
//    "+a", accum side): Wih1 + Whh1 + Wih2 = 48 frags = 192 regs. LDS: Whh2
//    (128 KB) + x/H double buffers (24 KB). 1 lgkm barrier/step. cell1 =
//    bs1 + Wih1*x + Whh1*h1 computed entirely on-CU (no gate materialization).
//  - NCH chosen from ws_size: 1 launch if ws >= 277 MB else 2 (proven-safe
//    142.6 MB footprint, same as R8).
// ---------------------------------------------------------------------------

typedef unsigned short u16;
typedef short bf16x8 __attribute__((ext_vector_type(8)));
typedef float f32x4 __attribute__((ext_vector_type(4)));
typedef unsigned short u16x4 __attribute__((ext_vector_type(4)));

#define MFMA16(a, b, c) __builtin_amdgcn_mfma_f32_16x16x32_bf16((a), (b), (c), 0, 0, 0)

#define GLOAD_LDS(gp, lp) __builtin_amdgcn_global_load_lds( \
    (const __attribute__((address_space(1))) unsigned int*)(const void*)(gp), \
    (__attribute__((address_space(3))) unsigned int*)(void*)(lp), 16, 0, 0)

#define LGKM_BAR do { \
  asm volatile("s_waitcnt lgkmcnt(0)" ::: "memory"); \
  __builtin_amdgcn_sched_barrier(0); \
  __builtin_amdgcn_s_barrier(); \
  __builtin_amdgcn_sched_barrier(0); \
} while (0)

__device__ __forceinline__ u16 f2bf(float f) {
  union { float f; unsigned u; } v; v.f = f;
  return (u16)((v.u + 0x7FFFu + ((v.u >> 16) & 1u)) >> 16);  // RNE
}
__device__ __forceinline__ float fsig(float x) { return 1.0f / (1.0f + __expf(-x)); }
__device__ __forceinline__ float ftanh(float x) { return 2.0f / (1.0f + __expf(-2.0f * x)) - 1.0f; }

// ---- ws layout (u16 / f32 indices) ---------------------------------------
#define WHH1_U  0         // 128 frags ((w*4+g)*4+kf)*512 : Whh1
#define WIH2_U  65536     // 128 frags : Wih2
#define WIH1_U  131072    // 128 frags : Wih1 (scan cell1)
#define WHH2_U  196608    // 128 frags : Whh2 (scan LDS image)
#define W1_U    262144    // 32 frags (n*2+kf)
#define W2_U    278528    // 64 frags (n*8+kf)
#define W3_U    311296    // 32 frags (n*4+kf)
#define WO1_U   327680    // 32 frags
#define WO2_U   344064    // 64 frags
#define WO3_U   376832    // 16 frags
#define BS1_F   192512    // f32[512] = bih1+bhh1
#define BS2_F   193024    // f32[512] = bih2+bhh2
#define STH1_U  393216    // bf16[4096*128]
#define STH2_U  917504
#define C1_F    720896    // f32[4096*128]
#define C2_F    1245184
#define XBUF_U  4194304   // bf16 x chunk buffer @ byte 8388608: [tl][4096][128]

// ======================= prep ==============================================
__global__ void prep_kernel(const float* __restrict__ Wih1, const float* __restrict__ Whh1,
                            const float* __restrict__ bih1, const float* __restrict__ bhh1,
                            const float* __restrict__ Wih2, const float* __restrict__ Whh2,
                            const float* __restrict__ bih2, const float* __restrict__ bhh2,
                            const float* __restrict__ W_in1, const float* __restrict__ W_in2,
                            const float* __restrict__ W_in3,
                            const float* __restrict__ W_out1, const float* __restrict__ W_out2,
                            const float* __restrict__ W_out3,
                            const float* __restrict__ h1_in, const float* __restrict__ h2_in,
                            const float* __restrict__ c1_in, const float* __restrict__ c2_in,
                            u16* __restrict__ wsu) {
  float* wsf = (float*)wsu;
  const int N_total = 2490368;
  int stride = gridDim.x * blockDim.x;
  for (int idx = blockIdx.x * blockDim.x + threadIdx.x; idx < N_total; idx += stride) {
    if (idx < 385024) {
      int within = idx & 511;
      int f = idx >> 9;
      int lane = within >> 3, e = within & 7;
      int lr = lane & 15, lg = lane >> 4;
      int k8 = lg * 8 + e;
      float v;
      if (f < 512) {                          // 4 cell matrices, same decode
        int kf = f & 3, g = (f >> 2) & 3, w = (f >> 4) & 7;
        int row = g * 128 + w * 16 + lr;
        int k = kf * 32 + k8;
        const float* M = (f < 128) ? Whh1 : (f < 256) ? Wih2 : (f < 384) ? Wih1 : Whh2;
        v = M[row * 128 + k];
      } else if (f < 544) {                   // W1
        int ff = f - 512; int kf = ff & 1, n = ff >> 1;
        v = W_in1[(n * 16 + lr) * 64 + kf * 32 + k8];
      } else if (f < 608) {                   // W2
        int ff = f - 544; int kf = ff & 7, n = ff >> 3;
        v = W_in2[(n * 16 + lr) * 256 + kf * 32 + k8];
      } else if (f < 640) {                   // W3
        int ff = f - 608; int kf = ff & 3, n = ff >> 2;
        v = W_in3[(n * 16 + lr) * 128 + kf * 32 + k8];
      } else if (f < 672) {                   // WO1
        int ff = f - 640; int kf = ff & 3, n = ff >> 2;
        v = W_out1[(n * 16 + lr) * 128 + kf * 32 + k8];
      } else if (f < 736) {                   // WO2
        int ff = f - 672; int kf = ff & 3, n = ff >> 2;
        v = W_out2[(n * 16 + lr) * 128 + kf * 32 + k8];
      } else {                                // WO3
        int ff = f - 736; int kf = ff & 7, n = ff >> 3;
        v = W_out3[(n * 16 + lr) * 256 + kf * 32 + k8];
      }
      wsu[idx] = f2bf(v);
    } else if (idx < 385536) {
      int i = idx - 385024; wsf[BS1_F + i] = bih1[i] + bhh1[i];
    } else if (idx < 386048) {
      int i = idx - 385536; wsf[BS2_F + i] = bih2[i] + bhh2[i];
    } else if (idx < 393216) {
      // pad
    } else if (idx < 917504) {
      int i = idx - 393216; wsu[STH1_U + i] = f2bf(h1_in[i]);
    } else if (idx < 1441792) {
      int i = idx - 917504; wsu[STH2_U + i] = f2bf(h2_in[i]);
    } else if (idx < 1966080) {
      int i = idx - 1441792; wsf[C1_F + i] = c1_in[i];
    } else {
      int i = idx - 1966080; wsf[C2_F + i] = c2_in[i];
    }
  }
}

// ======================= fc chunk ==========================================
// grid = 1024 * ntg blocks; block = 4 batches x 16 t = 64 rows.
__global__ __launch_bounds__(256, 2)
void fc_all(const float* __restrict__ seq,
            const float* __restrict__ b_in1, const float* __restrict__ b_in2,
            const float* __restrict__ b_in3,
            u16* __restrict__ wsu, int t0, int ntg) {
  __shared__ u16 SEQs[4096];
  __shared__ u16 F1s[16384];
  __shared__ u16 F2s[8192];
  __shared__ u16 XLs[8192];
  const int tid = threadIdx.x;
  const int wid = tid >> 6, lane = tid & 63;
  const int lr = lane & 15, lg = lane >> 4;
  const int bid_t = blockIdx.x % ntg, bid_b = blockIdx.x / ntg;
  const int b0c = bid_b * 4, t0c = t0 + bid_t * 16;

  // stage seq rows rho = b_local*16 + t_local
#pragma unroll
  for (int i = 0; i < 4; ++i) {
    int f = i * 1024 + tid * 4;
    int rho = f >> 6, k = f & 63;
    int b = b0c + (rho >> 4), tt = t0c + (rho & 15);
    float4 v = *(const float4*)(seq + ((size_t)b * 256 + tt) * 64 + k);
    u16x4 o = { f2bf(v.x), f2bf(v.y), f2bf(v.z), f2bf(v.w) };
    *(u16x4*)&SEQs[(rho * 64 + k) ^ ((rho & 7) << 3)] = o;
  }
  __syncthreads();

  { // L1: [64,256], K=64
    f32x4 a1[4][4] = {};
#pragma unroll
    for (int kf = 0; kf < 2; ++kf) {
      bf16x8 A[4];
#pragma unroll
      for (int rt = 0; rt < 4; ++rt) {
        int r = 16 * rt + lr;
        A[rt] = *(const bf16x8*)&SEQs[(r * 64 + (kf * 4 + lg) * 8) ^ ((r & 7) << 3)];
      }
#pragma unroll
      for (int n = 0; n < 4; ++n) {
        bf16x8 B = *(const bf16x8*)(wsu + W1_U + (size_t)(((4 * wid + n) * 2 + kf) * 512) + lane * 8);
#pragma unroll
        for (int rt = 0; rt < 4; ++rt) a1[rt][n] = MFMA16(A[rt], B, a1[rt][n]);
      }
    }
#pragma unroll
    for (int n = 0; n < 4; ++n) {
      float bb = b_in1[(4 * wid + n) * 16 + lr];
#pragma unroll
      for (int rt = 0; rt < 4; ++rt)
#pragma unroll
        for (int j = 0; j < 4; ++j) {
          int r = 16 * rt + lg * 4 + j, c = (4 * wid + n) * 16 + lr;
          F1s[(r * 256 + c) ^ ((r & 7) << 3)] = f2bf(fmaxf(a1[rt][n][j] + bb, 0.f));
        }
    }
  }
  __syncthreads();

  { // L2: [64,128], K=256
    f32x4 a2[4][2] = {};
#pragma unroll
    for (int kf = 0; kf < 8; ++kf) {
      bf16x8 A[4];
#pragma unroll
      for (int rt = 0; rt < 4; ++rt) {
        int r = 16 * rt + lr;
        A[rt] = *(const bf16x8*)&F1s[(r * 256 + (kf * 4 + lg) * 8) ^ ((r & 7) << 3)];
      }
#pragma unroll
      for (int n = 0; n < 2; ++n) {
        bf16x8 B = *(const bf16x8*)(wsu + W2_U + (size_t)(((2 * wid + n) * 8 + kf) * 512) + lane * 8);
#pragma unroll
        for (int rt = 0; rt < 4; ++rt) a2[rt][n] = MFMA16(A[rt], B, a2[rt][n]);
      }
    }
#pragma unroll
    for (int n = 0; n < 2; ++n) {
      float bb = b_in2[(2 * wid + n) * 16 + lr];
#pragma unroll
      for (int rt = 0; rt < 4; ++rt)
#pragma unroll
        for (int j = 0; j < 4; ++j) {
          int r = 16 * rt + lg * 4 + j, c = (2 * wid + n) * 16 + lr;
          F2s[(r * 128 + c) ^ ((r & 7) << 3)] = f2bf(fmaxf(a2[rt][n][j] + bb, 0.f));
        }
    }
  }
  __syncthreads();

  { // L3: [64,128], K=128 -> XLs
    f32x4 a3[4][2] = {};
#pragma unroll
    for (int kf = 0; kf < 4; ++kf) {
      bf16x8 A[4];
#pragma unroll
      for (int rt = 0; rt < 4; ++rt) {
        int r = 16 * rt + lr;
        A[rt] = *(const bf16x8*)&F2s[(r * 128 + (kf * 4 + lg) * 8) ^ ((r & 7) << 3)];
      }
#pragma unroll
      for (int n = 0; n < 2; ++n) {
        bf16x8 B = *(const bf16x8*)(wsu + W3_U + (size_t)(((2 * wid + n) * 4 + kf) * 512) + lane * 8);
#pragma unroll
        for (int rt = 0; rt < 4; ++rt) a3[rt][n] = MFMA16(A[rt], B, a3[rt][n]);
      }
    }
#pragma unroll
    for (int n = 0; n < 2; ++n) {
      float bb = b_in3[(2 * wid + n) * 16 + lr];
#pragma unroll
      for (int rt = 0; rt < 4; ++rt)
#pragma unroll
        for (int j = 0; j < 4; ++j) {
          int r = 16 * rt + lg * 4 + j, c = (2 * wid + n) * 16 + lr;
          XLs[(r * 128 + c) ^ ((r & 7) << 3)] = f2bf(fmaxf(a3[rt][n][j] + bb, 0.f));
        }
    }
  }
  __syncthreads();

  { // copy XLs -> XBUF (coalesced 256 B per 4-thread group)
    int row = tid >> 2, seg = tid & 3;
    int b = b0c + (row >> 4), tl = bid_t * 16 + (row & 15);
    u16* dst = wsu + XBUF_U + ((size_t)tl * 4096 + b) * 128 + seg * 32;
#pragma unroll
    for (int g8 = 0; g8 < 4; ++g8) {
      int c = seg * 32 + g8 * 8;
      bf16x8 v = *(const bf16x8*)&XLs[(row * 128 + c) ^ ((row & 7) << 3)];
      *(bf16x8*)(dst + g8 * 8) = v;
    }
  }
}

// ======================= scan ==============================================
__global__ __launch_bounds__(512, 1)
void scan_kernel(u16* __restrict__ wsu, float* __restrict__ out,
                 const float* __restrict__ b_out1, const float* __restrict__ b_out2,
                 const float* __restrict__ b_out3, int nsteps, int last) {
  __shared__ u16 Wl[65536];                   // 128 KB Whh2 B-frags
  __shared__ u16 XB[2][2048];                 // x double buffer [16][128]
  __shared__ u16 H1d[2][2048], H2d[2][2048];

  float* wsf = (float*)wsu;
  const int tid = threadIdx.x;
  const int wid = tid >> 6, lane = tid & 63;
  const int lr = lane & 15, lg = lane >> 4;
  const int b0 = blockIdx.x * 16;
  const int r5 = tid >> 5, c5 = (tid & 31) * 4;
  const int swl = (r5 * 128 + c5) ^ ((r5 & 7) << 3);

  // ---- 48 register frags (Whh1, Wih2, Wih1), pinned to accum side ----
  bf16x8 wA[4][4], wB[4][4], wX[4][4];
#pragma unroll
  for (int g = 0; g < 4; ++g)
#pragma unroll
    for (int kf = 0; kf < 4; ++kf) {
      size_t fo = (size_t)(((wid * 4 + g) * 4 + kf) * 512) + lane * 8;
      wA[g][kf] = *(const bf16x8*)(wsu + WHH1_U + fo);
      wB[g][kf] = *(const bf16x8*)(wsu + WIH2_U + fo);
      wX[g][kf] = *(const bf16x8*)(wsu + WIH1_U + fo);
    }
#pragma unroll
  for (int g = 0; g < 4; ++g)
#pragma unroll
    for (int kf = 0; kf < 4; ++kf) {
      asm volatile("" : "+a"(wA[g][kf]));
      asm volatile("" : "+a"(wB[g][kf]));
      asm volatile("" : "+a"(wX[g][kf]));
    }

  // ---- Whh2 -> Wl ----
#pragma unroll
  for (int i = 0; i < 16; ++i)
    GLOAD_LDS(wsu + WHH2_U + (wid * 16 + i) * 512 + lane * 8, &Wl[(wid * 16 + i) * 512]);

  // ---- state + x(0), x(1) ----
  *(u16x4*)&H1d[0][swl] = *(const u16x4*)(wsu + STH1_U + (size_t)(b0 + r5) * 128 + c5);
  *(u16x4*)&H2d[0][swl] = *(const u16x4*)(wsu + STH2_U + (size_t)(b0 + r5) * 128 + c5);
  *(u16x4*)&XB[0][swl]  = *(const u16x4*)(wsu + XBUF_U + ((size_t)0 * 4096 + b0 + r5) * 128 + c5);
  *(u16x4*)&XB[1][swl]  = *(const u16x4*)(wsu + XBUF_U + ((size_t)1 * 4096 + b0 + r5) * 128 + c5);
  float cs1[4], cs2[4], bc1[4], bc2[4];
#pragma unroll
  for (int j = 0; j < 4; ++j) {
    cs1[j] = wsf[C1_F + (size_t)(b0 + lg * 4 + j) * 128 + 16 * wid + lr];
    cs2[j] = wsf[C2_F + (size_t)(b0 + lg * 4 + j) * 128 + 16 * wid + lr];
  }
#pragma unroll
  for (int g = 0; g < 4; ++g) {
    bc1[g] = wsf[BS1_F + g * 128 + 16 * wid + lr];
    bc2[g] = wsf[BS2_F + g * 128 + 16 * wid + lr];
  }
  __syncthreads();   // staging + Wl drained

  auto frag = [&](const u16* buf, int kg) -> bf16x8 {
    return *(const bf16x8*)&buf[(lr * 128 + kg * 8) ^ ((lr & 7) << 3)];
  };

  // ================= scan: 1 barrier/step =================
#pragma unroll 2
  for (int tl = 0; tl < nsteps; ++tl) {
    const int p = tl & 1, q = p ^ 1;
    int tn = tl + 2; if (tn > nsteps - 1) tn = nsteps - 1;
    u16x4 xn = *(const u16x4*)(wsu + XBUF_U + ((size_t)tn * 4096 + b0 + r5) * 128 + c5);

    // -- phase 1: cell1 = bs1 + Wih1*x(t) + Whh1*h1(t-1) --
    f32x4 acc[4];
#pragma unroll
    for (int g = 0; g < 4; ++g) acc[g] = (f32x4){ bc1[g], bc1[g], bc1[g], bc1[g] };
    bf16x8 xf[4], h1f[4];
#pragma unroll
    for (int kf = 0; kf < 4; ++kf) {
      xf[kf]  = frag(XB[p], kf * 4 + lg);
      h1f[kf] = frag(H1d[p], kf * 4 + lg);
    }
#pragma unroll
    for (int kf = 0; kf < 4; ++kf)
#pragma unroll
      for (int g = 0; g < 4; ++g) acc[g] = MFMA16(xf[kf], wX[g][kf], acc[g]);
#pragma unroll
    for (int kf = 0; kf < 4; ++kf)
#pragma unroll
      for (int g = 0; g < 4; ++g) acc[g] = MFMA16(h1f[kf], wA[g][kf], acc[g]);
    u16 hv[4];
#pragma unroll
    for (int j = 0; j < 4; ++j) {
      float cn = fsig(acc[1][j]) * cs1[j] + fsig(acc[0][j]) * ftanh(acc[2][j]);
      cs1[j] = cn;
      hv[j] = f2bf(fsig(acc[3][j]) * ftanh(cn));
    }
#pragma unroll
    for (int j = 0; j < 4; ++j) {
      int r = lg * 4 + j;
      H1d[q][(r * 128 + 16 * wid + lr) ^ ((r & 7) << 3)] = hv[j];
    }
    LGKM_BAR;   // h1(t) visible; all phase-1 reads of XB[p]/H1d[p] complete

    // -- phase 2: cell2 = bs2 + Wih2*h1(t) + Whh2*h2(t-1) --
    f32x4 acd[4];
#pragma unroll
    for (int g = 0; g < 4; ++g) acd[g] = (f32x4){ bc2[g], bc2[g], bc2[g], bc2[g] };
#pragma unroll
    for (int kf = 0; kf < 4; ++kf) {
      bf16x8 h1n = frag(H1d[q], kf * 4 + lg);
#pragma unroll
      for (int g = 0; g < 4; ++g) acd[g] = MFMA16(h1n, wB[g][kf], acd[g]);
    }
#pragma unroll
    for (int kf = 0; kf < 4; ++kf) {
      bf16x8 h2f = frag(H2d[p], kf * 4 + lg);
#pragma unroll
      for (int g = 0; g < 4; ++g) {
        bf16x8 B = *(const bf16x8*)&Wl[(((wid * 4 + g) * 4 + kf) * 512) + lane * 8];
        acd[g] = MFMA16(h2f, B, acd[g]);
      }
    }
#pragma unroll
    for (int j = 0; j < 4; ++j) {
      float cn = fsig(acd[1][j]) * cs2[j] + fsig(acd[0][j]) * ftanh(acd[2][j]);
      cs2[j] = cn;
      hv[j] = f2bf(fsig(acd[3][j]) * ftanh(cn));
    }
#pragma unroll
    for (int j = 0; j < 4; ++j) {
      int r = lg * 4 + j;
      H2d[q][(r * 128 + 16 * wid + lr) ^ ((r & 7) << 3)] = hv[j];
    }
    *(u16x4*)&XB[p][swl] = xn;   // x(t+2); XB[p] reads done pre-BAR(t)
    // no second barrier: next phase1 reads XB[q]/H1d[q] (cross BAR(t)) and
    // writes H1d[p] (reads of it completed pre-BAR(t)).
  }
  LGKM_BAR;   // final h writes visible

  if (!last) {
    *(u16x4*)(wsu + STH1_U + (size_t)(b0 + r5) * 128 + c5) = *(const u16x4*)&H1d[0][swl];
    *(u16x4*)(wsu + STH2_U + (size_t)(b0 + r5) * 128 + c5) = *(const u16x4*)&H2d[0][swl];
#pragma unroll
    for (int j = 0; j < 4; ++j) {
      wsf[C1_F + (size_t)(b0 + lg * 4 + j) * 128 + 16 * wid + lr] = cs1[j];
      wsf[C2_F + (size_t)(b0 + lg * 4 + j) * 128 + 16 * wid + lr] = cs2[j];
    }
  } else {
    // ---- head: Y1 -> H1d[1]; Y2 -> H2d[1] (lo) | H1d[0] (hi); Y3 -> out ----
    {
      f32x4 y1 = {};
#pragma unroll
      for (int kf = 0; kf < 4; ++kf) {
        bf16x8 A = frag(H2d[0], kf * 4 + lg);
        bf16x8 B = *(const bf16x8*)(wsu + WO1_U + (size_t)((wid * 4 + kf) * 512) + lane * 8);
        y1 = MFMA16(A, B, y1);
      }
      float bo1 = b_out1[wid * 16 + lr];
      LGKM_BAR;
#pragma unroll
      for (int j = 0; j < 4; ++j) {
        int r = lg * 4 + j;
        H1d[1][(r * 128 + 16 * wid + lr) ^ ((r & 7) << 3)] = f2bf(fmaxf(y1[j] + bo1, 0.f));
      }
      LGKM_BAR;
    }
    {
      f32x4 y2[2] = {};
#pragma unroll
      for (int kf = 0; kf < 4; ++kf) {
        bf16x8 A = frag(H1d[1], kf * 4 + lg);
#pragma unroll
        for (int n = 0; n < 2; ++n) {
          bf16x8 B = *(const bf16x8*)(wsu + WO2_U + (size_t)(((2 * wid + n) * 4 + kf) * 512) + lane * 8);
          y2[n] = MFMA16(A, B, y2[n]);
        }
      }
      LGKM_BAR;
#pragma unroll
      for (int n = 0; n < 2; ++n)
#pragma unroll
        for (int j = 0; j < 4; ++j) {
          int c = (2 * wid + n) * 16 + lr;
          float v = fmaxf(y2[n][j] + b_out2[c], 0.f);
          u16* buf = (c < 128) ? &H2d[1][0] : &H1d[0][0];
          int cc = c & 127, r = lg * 4 + j;
          buf[(r * 128 + cc) ^ ((r & 7) << 3)] = f2bf(v);
        }
      LGKM_BAR;
    }
    if (wid < 2) {
      f32x4 y3 = {};
#pragma unroll
      for (int kf = 0; kf < 8; ++kf) {
        const u16* ab = (kf < 4) ? &H2d[1][0] : &H1d[0][0];
        bf16x8 A = frag(ab, (kf & 3) * 4 + lg);
        bf16x8 B = *(const bf16x8*)(wsu + WO3_U + (size_t)((wid * 8 + kf) * 512) + lane * 8);
        y3 = MFMA16(A, B, y3);
      }
      float bo3 = b_out3[wid * 16 + lr];
#pragma unroll
      for (int j = 0; j < 4; ++j)
        out[(size_t)(b0 + lg * 4 + j) * 32 + wid * 16 + lr] = y3[j] + bo3;
    }
  }
}

// ======================= host ==============================================
extern "C" void kernel_launch(void* const* d_in, const int* in_sizes, int n_in,
                              void* d_out, int out_size, void* d_ws, size_t ws_size,
                              hipStream_t stream) {
  (void)in_sizes; (void)n_in; (void)out_size;
  const float* seq    = (const float*)d_in[0];
  const float* h1     = (const float*)d_in[1];
  const float* c1     = (const float*)d_in[2];
  const float* h2     = (const float*)d_in[3];
  const float* c2     = (const float*)d_in[4];
  const float* W_in1  = (const float*)d_in[5];
  const float* b_in1  = (const float*)d_in[6];
  const float* W_in2  = (const float*)d_in[7];
  const float* b_in2  = (const float*)d_in[8];
  const float* W_in3  = (const float*)d_in[9];
  const float* b_in3  = (const float*)d_in[10];
  const float* Wih1   = (const float*)d_in[11];
  const float* Whh1   = (const float*)d_in[12];
  const float* bih1   = (const float*)d_in[13];
  const float* bhh1   = (const float*)d_in[14];
  const float* Wih2   = (const float*)d_in[15];
  const float* Whh2   = (const float*)d_in[16];
  const float* bih2   = (const float*)d_in[17];
  const float* bhh2   = (const float*)d_in[18];
  const float* W_out1 = (const float*)d_in[19];
  const float* b_out1 = (const float*)d_in[20];
  const float* W_out2 = (const float*)d_in[21];
  const float* b_out2 = (const float*)d_in[22];
  const float* W_out3 = (const float*)d_in[23];
  const float* b_out3 = (const float*)d_in[24];
  u16* wsu = (u16*)d_ws;
  float* out = (float*)d_out;

  // pick chunking from ws_size: 1 launch if x for all 256 t fits (~277 MB),
  // else 2 launches at 128 t (134 MB x-chunk: R8-proven-safe footprint).
  const size_t need1 = 8388608ull + (size_t)256 * 4096 * 128 * 2;
  const int nch = (ws_size >= need1) ? 1 : 2;
  const int tc = 256 / nch;
  const int ntg = tc / 16;

  hipLaunchKernelGGL(prep_kernel, dim3(512), dim3(256), 0, stream,
                     Wih1, Whh1, bih1, bhh1, Wih2, Whh2, bih2, bhh2,
                     W_in1, W_in2, W_in3, W_out1, W_out2, W_out3,
                     h1, h2, c1, c2, wsu);
  for (int k = 0; k < nch; ++k) {
    hipLaunchKernelGGL(fc_all, dim3(1024 * ntg), dim3(256), 0, stream,
                       seq, b_in1, b_in2, b_in3, wsu, k * tc, ntg);
    hipLaunchKernelGGL(scan_kernel, dim3(256), dim3(512), 0, stream,
                       wsu, out, b_out1, b_out2, b_out3, tc, (k == nch - 1) ? 1 : 0);
  }
}

// Round 10
// 1669.237 us; speedup vs baseline: 1.2556x; 1.1430x over previous
//
#include <hip/hip_runtime.h>

// ---------------------------------------------------------------------------
// R10: R8 structure (proven register-budget-feasible: 2 matrices = 128 accum
// regs resident, Whh2 in LDS, g1x precomputed by fc) + ONE fix: the elementwise
// sigmoid/tanh used IEEE float DIVISION (no -ffast-math) -> ~12 instr + ~50cyc
// serial chain each, 5 per gate-element = the structure-invariant ~5.8us/step
// floor of R5-R9. Replaced with v_rcp_f32 via __builtin_amdgcn_rcpf.
// ---------------------------------------------------------------------------

typedef unsigned short u16;
typedef short bf16x8 __attribute__((ext_vector_type(8)));
typedef float f32x4 __attribute__((ext_vector_type(4)));
typedef unsigned short u16x4 __attribute__((ext_vector_type(4)));

#define MFMA16(a, b, c) __builtin_amdgcn_mfma_f32_16x16x32_bf16((a), (b), (c), 0, 0, 0)

#define GLOAD_LDS(gp, lp) __builtin_amdgcn_global_load_lds( \
    (const __attribute__((address_space(1))) unsigned int*)(const void*)(gp), \
    (__attribute__((address_space(3))) unsigned int*)(void*)(lp), 16, 0, 0)

#define LGKM_BAR do { \
  asm volatile("s_waitcnt lgkmcnt(0)" ::: "memory"); \
  __builtin_amdgcn_sched_barrier(0); \
  __builtin_amdgcn_s_barrier(); \
  __builtin_amdgcn_sched_barrier(0); \
} while (0)

__device__ __forceinline__ u16 f2bf(float f) {
  union { float f; unsigned u; } v; v.f = f;
  return (u16)((v.u + 0x7FFFu + ((v.u >> 16) & 1u)) >> 16);  // RNE
}
__device__ __forceinline__ float b2f(u16 v) {
  union { unsigned u; float f; } x; x.u = ((unsigned)v) << 16; return x.f;
}
// rcp-based activations: __expf -> v_exp_f32 (native), rcpf -> v_rcp_f32.
// IEEE-div-free (the R5-R9 VALU poison). Graceful at +-inf: rcp(inf)=0.
__device__ __forceinline__ float fsig(float x) {
  return __builtin_amdgcn_rcpf(1.0f + __expf(-x));
}
__device__ __forceinline__ float ftanh(float x) {
  return 2.0f * __builtin_amdgcn_rcpf(1.0f + __expf(-2.0f * x)) - 1.0f;
}

// ---- ws layout (u16 / f32 indices) ---------------------------------------
#define WHH1_U  0         // 128 frags ((w*4+g)*4+kf)*512 : Whh1
#define WIH2_U  65536     // 128 frags : Wih2
#define WHH2_U  131072    // 128 frags (w*16+g*4+kf)*512 : Whh2 (LDS image)
#define WIH1_U  196608    // 128 frags (n*4+kf)*512, n=0..31 : Wih1 (fc L4)
#define W1_U    262144    // 32 frags (n*2+kf)
#define W2_U    278528    // 64 frags (n*8+kf)
#define W3_U    311296    // 32 frags (n*4+kf)
#define WO1_U   327680    // 32 frags
#define WO2_U   344064    // 64 frags
#define WO3_U   376832    // 16 frags
#define BS1_F   192512    // f32[512] = bih1+bhh1 (folded into g1x)
#define BS2_F   193024    // f32[512] = bih2+bhh2
#define STH1_U  393216    // bf16[4096*128]
#define STH2_U  917504
#define C1_F    720896    // f32[4096*128]
#define C2_F    1245184
#define G1X_U   4194304   // bf16 g1x chunk buffer @ byte 8388608, 134MB
#define TC      32
#define NCH     8

// g1x u16 index: (((((tl*256+blk)*4+slg)*4+g)*8+swid)*16+slr)*4 + sj
//   b = blk*16 + slg*4 + sj ; c = g*128 + swid*16 + slr

// ======================= prep ==============================================
__global__ void prep_kernel(const float* __restrict__ Wih1, const float* __restrict__ Whh1,
                            const float* __restrict__ bih1, const float* __restrict__ bhh1,
                            const float* __restrict__ Wih2, const float* __restrict__ Whh2,
                            const float* __restrict__ bih2, const float* __restrict__ bhh2,
                            const float* __restrict__ W_in1, const float* __restrict__ W_in2,
                            const float* __restrict__ W_in3,
                            const float* __restrict__ W_out1, const float* __restrict__ W_out2,
                            const float* __restrict__ W_out3,
                            const float* __restrict__ h1_in, const float* __restrict__ h2_in,
                            const float* __restrict__ c1_in, const float* __restrict__ c2_in,
                            u16* __restrict__ wsu) {
  float* wsf = (float*)wsu;
  const int N_total = 2490368;
  int stride = gridDim.x * blockDim.x;
  for (int idx = blockIdx.x * blockDim.x + threadIdx.x; idx < N_total; idx += stride) {
    if (idx < 385024) {
      int within = idx & 511;
      int f = idx >> 9;
      int lane = within >> 3, e = within & 7;
      int lr = lane & 15, lg = lane >> 4;
      int k8 = lg * 8 + e;
      float v;
      if (f < 128) {                          // WHH1
        int kf = f & 3, g = (f >> 2) & 3, w = f >> 4;
        v = Whh1[(g * 128 + w * 16 + lr) * 128 + kf * 32 + k8];
      } else if (f < 256) {                   // WIH2
        int ff = f - 128; int kf = ff & 3, g = (ff >> 2) & 3, w = ff >> 4;
        v = Wih2[(g * 128 + w * 16 + lr) * 128 + kf * 32 + k8];
      } else if (f < 384) {                   // WHH2
        int ff = f - 256; int kf = ff & 3, g = (ff >> 2) & 3, w = ff >> 4;
        v = Whh2[(g * 128 + w * 16 + lr) * 128 + kf * 32 + k8];
      } else if (f < 512) {                   // WIH1 (fc L4)
        int ff = f - 384; int kf = ff & 3, n = ff >> 2;
        v = Wih1[(n * 16 + lr) * 128 + kf * 32 + k8];
      } else if (f < 544) {                   // W1
        int ff = f - 512; int kf = ff & 1, n = ff >> 1;
        v = W_in1[(n * 16 + lr) * 64 + kf * 32 + k8];
      } else if (f < 608) {                   // W2
        int ff = f - 544; int kf = ff & 7, n = ff >> 3;
        v = W_in2[(n * 16 + lr) * 256 + kf * 32 + k8];
      } else if (f < 640) {                   // W3
        int ff = f - 608; int kf = ff & 3, n = ff >> 2;
        v = W_in3[(n * 16 + lr) * 128 + kf * 32 + k8];
      } else if (f < 672) {                   // WO1
        int ff = f - 640; int kf = ff & 3, n = ff >> 2;
        v = W_out1[(n * 16 + lr) * 128 + kf * 32 + k8];
      } else if (f < 736) {                   // WO2
        int ff = f - 672; int kf = ff & 3, n = ff >> 2;
        v = W_out2[(n * 16 + lr) * 128 + kf * 32 + k8];
      } else {                                // WO3
        int ff = f - 736; int kf = ff & 7, n = ff >> 3;
        v = W_out3[(n * 16 + lr) * 256 + kf * 32 + k8];
      }
      wsu[idx] = f2bf(v);
    } else if (idx < 385536) {
      int i = idx - 385024; wsf[BS1_F + i] = bih1[i] + bhh1[i];
    } else if (idx < 386048) {
      int i = idx - 385536; wsf[BS2_F + i] = bih2[i] + bhh2[i];
    } else if (idx < 393216) {
      // pad
    } else if (idx < 917504) {
      int i = idx - 393216; wsu[STH1_U + i] = f2bf(h1_in[i]);
    } else if (idx < 1441792) {
      int i = idx - 917504; wsu[STH2_U + i] = f2bf(h2_in[i]);
    } else if (idx < 1966080) {
      int i = idx - 1441792; wsf[C1_F + i] = c1_in[i];
    } else {
      int i = idx - 1966080; wsf[C2_F + i] = c2_in[i];
    }
  }
}

// ======================= fc chunk ==========================================
// 2048 blocks (1024 b-groups x 2 t-halves) x 256 thr; block = 4 b x 16 t.
__global__ __launch_bounds__(256, 2)
void fc_chunk(const float* __restrict__ seq,
              const float* __restrict__ b_in1, const float* __restrict__ b_in2,
              const float* __restrict__ b_in3,
              u16* __restrict__ wsu, int t0) {
  __shared__ u16 SEQs[4096];   // [64][64]
  __shared__ u16 F1s[16384];   // [64][256]
  __shared__ u16 F2s[8192];    // [64][128]
  __shared__ u16 XLs[8192];    // [64][128] (L3 out)
  const int tid = threadIdx.x;
  const int wid = tid >> 6, lane = tid & 63;
  const int lr = lane & 15, lg = lane >> 4;
  const int bid_t = blockIdx.x & 1, bid_b = blockIdx.x >> 1;
  const int b0c = bid_b * 4, t0c = t0 + bid_t * 16;
  const float* bs1f = (const float*)wsu + BS1_F;

  // stage seq rows rho=(b_local*16+t_local), f32 -> bf16 swizzled
#pragma unroll
  for (int i = 0; i < 4; ++i) {
    int f = i * 1024 + tid * 4;
    int rho = f >> 6, k = f & 63;
    int b = b0c + (rho >> 4), tt = t0c + (rho & 15);
    float4 v = *(const float4*)(seq + ((size_t)b * 256 + tt) * 64 + k);
    u16x4 o = { f2bf(v.x), f2bf(v.y), f2bf(v.z), f2bf(v.w) };
    *(u16x4*)&SEQs[(rho * 64 + k) ^ ((rho & 7) << 3)] = o;
  }
  __syncthreads();

  { // L1: [64,256], K=64
    f32x4 a1[4][4] = {};
#pragma unroll
    for (int kf = 0; kf < 2; ++kf) {
      bf16x8 A[4];
#pragma unroll
      for (int rt = 0; rt < 4; ++rt) {
        int r = 16 * rt + lr;
        A[rt] = *(const bf16x8*)&SEQs[(r * 64 + (kf * 4 + lg) * 8) ^ ((r & 7) << 3)];
      }
#pragma unroll
      for (int n = 0; n < 4; ++n) {
        bf16x8 B = *(const bf16x8*)(wsu + W1_U + (size_t)(((4 * wid + n) * 2 + kf) * 512) + lane * 8);
#pragma unroll
        for (int rt = 0; rt < 4; ++rt) a1[rt][n] = MFMA16(A[rt], B, a1[rt][n]);
      }
    }
#pragma unroll
    for (int n = 0; n < 4; ++n) {
      float bb = b_in1[(4 * wid + n) * 16 + lr];
#pragma unroll
      for (int rt = 0; rt < 4; ++rt)
#pragma unroll
        for (int j = 0; j < 4; ++j) {
          int r = 16 * rt + lg * 4 + j, c = (4 * wid + n) * 16 + lr;
          F1s[(r * 256 + c) ^ ((r & 7) << 3)] = f2bf(fmaxf(a1[rt][n][j] + bb, 0.f));
        }
    }
  }
  __syncthreads();

  { // L2: [64,128], K=256
    f32x4 a2[4][2] = {};
#pragma unroll
    for (int kf = 0; kf < 8; ++kf) {
      bf16x8 A[4];
#pragma unroll
      for (int rt = 0; rt < 4; ++rt) {
        int r = 16 * rt + lr;
        A[rt] = *(const bf16x8*)&F1s[(r * 256 + (kf * 4 + lg) * 8) ^ ((r & 7) << 3)];
      }
#pragma unroll
      for (int n = 0; n < 2; ++n) {
        bf16x8 B = *(const bf16x8*)(wsu + W2_U + (size_t)(((2 * wid + n) * 8 + kf) * 512) + lane * 8);
#pragma unroll
        for (int rt = 0; rt < 4; ++rt) a2[rt][n] = MFMA16(A[rt], B, a2[rt][n]);
      }
    }
#pragma unroll
    for (int n = 0; n < 2; ++n) {
      float bb = b_in2[(2 * wid + n) * 16 + lr];
#pragma unroll
      for (int rt = 0; rt < 4; ++rt)
#pragma unroll
        for (int j = 0; j < 4; ++j) {
          int r = 16 * rt + lg * 4 + j, c = (2 * wid + n) * 16 + lr;
          F2s[(r * 128 + c) ^ ((r & 7) << 3)] = f2bf(fmaxf(a2[rt][n][j] + bb, 0.f));
        }
    }
  }
  __syncthreads();

  { // L3: [64,128], K=128 -> XLs
    f32x4 a3[4][2] = {};
#pragma unroll
    for (int kf = 0; kf < 4; ++kf) {
      bf16x8 A[4];
#pragma unroll
      for (int rt = 0; rt < 4; ++rt) {
        int r = 16 * rt + lr;
        A[rt] = *(const bf16x8*)&F2s[(r * 128 + (kf * 4 + lg) * 8) ^ ((r & 7) << 3)];
      }
#pragma unroll
      for (int n = 0; n < 2; ++n) {
        bf16x8 B = *(const bf16x8*)(wsu + W3_U + (size_t)(((2 * wid + n) * 4 + kf) * 512) + lane * 8);
#pragma unroll
        for (int rt = 0; rt < 4; ++rt) a3[rt][n] = MFMA16(A[rt], B, a3[rt][n]);
      }
    }
#pragma unroll
    for (int n = 0; n < 2; ++n) {
      float bb = b_in3[(2 * wid + n) * 16 + lr];
#pragma unroll
      for (int rt = 0; rt < 4; ++rt)
#pragma unroll
        for (int j = 0; j < 4; ++j) {
          int r = 16 * rt + lg * 4 + j, c = (2 * wid + n) * 16 + lr;
          XLs[(r * 128 + c) ^ ((r & 7) << 3)] = f2bf(fmaxf(a3[rt][n][j] + bb, 0.f));
        }
    }
  }
  __syncthreads();

  { // L4: g1x = x @ Wih1^T + bs1 : [64,512], K=128 -> global (fragment order)
    f32x4 a4[4][8] = {};
#pragma unroll
    for (int kf = 0; kf < 4; ++kf) {
      bf16x8 A[4];
#pragma unroll
      for (int rt = 0; rt < 4; ++rt) {
        int r = 16 * rt + lr;
        A[rt] = *(const bf16x8*)&XLs[(r * 128 + (kf * 4 + lg) * 8) ^ ((r & 7) << 3)];
      }
#pragma unroll
      for (int n = 0; n < 8; ++n) {
        bf16x8 B = *(const bf16x8*)(wsu + WIH1_U + (size_t)(((wid * 8 + n) * 4 + kf) * 512) + lane * 8);
#pragma unroll
        for (int rt = 0; rt < 4; ++rt) a4[rt][n] = MFMA16(A[rt], B, a4[rt][n]);
      }
    }
    const int blk = bid_b >> 2, slg = bid_b & 3;
#pragma unroll
    for (int n = 0; n < 8; ++n) {
      float bb = bs1f[(wid * 8 + n) * 16 + lr];
#pragma unroll
      for (int j = 0; j < 4; ++j) {
        int tl = bid_t * 16 + lg * 4 + j;
        u16x4 o = { f2bf(a4[0][n][j] + bb), f2bf(a4[1][n][j] + bb),
                    f2bf(a4[2][n][j] + bb), f2bf(a4[3][n][j] + bb) };
        size_t au = (size_t)G1X_U +
            ((((((size_t)tl * 256 + blk) * 4 + slg) * 4 + wid) * 8 + n) * 16 + lr) * 4;
        *(u16x4*)(wsu + au) = o;
      }
    }
  }
}

// ======================= scan chunk ========================================
__global__ __launch_bounds__(512, 1)
void scan_chunk(u16* __restrict__ wsu, float* __restrict__ out,
                const float* __restrict__ b_out1, const float* __restrict__ b_out2,
                const float* __restrict__ b_out3, int last) {
  __shared__ u16 Wl[65536];                   // 128 KB Whh2 B-frags
  __shared__ u16 H1d[2][2048], H2d[2][2048];  // 16 KB

  float* wsf = (float*)wsu;
  const int tid = threadIdx.x;
  const int wid = tid >> 6, lane = tid & 63;
  const int lr = lane & 15, lg = lane >> 4;
  const int b0 = blockIdx.x * 16;
  const int blkid = blockIdx.x;
  const int r5 = tid >> 5, c5 = (tid & 31) * 4;
  const int swl = (r5 * 128 + c5) ^ ((r5 & 7) << 3);

  // ---- register weights (128 accum regs: exactly the per-wave budget) ----
  bf16x8 wA[4][4], wB[4][4];   // Whh1, Wih2
#pragma unroll
  for (int g = 0; g < 4; ++g)
#pragma unroll
    for (int kf = 0; kf < 4; ++kf) {
      wA[g][kf] = *(const bf16x8*)(wsu + WHH1_U + (size_t)(((wid * 4 + g) * 4 + kf) * 512) + lane * 8);
      wB[g][kf] = *(const bf16x8*)(wsu + WIH2_U + (size_t)(((wid * 4 + g) * 4 + kf) * 512) + lane * 8);
    }
#pragma unroll
  for (int g = 0; g < 4; ++g)
#pragma unroll
    for (int kf = 0; kf < 4; ++kf) {
      asm volatile("" : "+a"(wA[g][kf]));
      asm volatile("" : "+a"(wB[g][kf]));
    }

  // ---- Whh2 -> Wl ----
#pragma unroll
  for (int i = 0; i < 16; ++i)
    GLOAD_LDS(wsu + WHH2_U + (wid * 16 + i) * 512 + lane * 8, &Wl[(wid * 16 + i) * 512]);

  // ---- state ----
  *(u16x4*)&H1d[0][swl] = *(const u16x4*)(wsu + STH1_U + (size_t)(b0 + r5) * 128 + c5);
  *(u16x4*)&H2d[0][swl] = *(const u16x4*)(wsu + STH2_U + (size_t)(b0 + r5) * 128 + c5);
  float cs1[4], cs2[4], bc2[4];
#pragma unroll
  for (int j = 0; j < 4; ++j) {
    cs1[j] = wsf[C1_F + (size_t)(b0 + lg * 4 + j) * 128 + 16 * wid + lr];
    cs2[j] = wsf[C2_F + (size_t)(b0 + lg * 4 + j) * 128 + 16 * wid + lr];
  }
#pragma unroll
  for (int g = 0; g < 4; ++g) bc2[g] = wsf[BS2_F + g * 128 + 16 * wid + lr];

  // ---- g1x(0) prefetch ----
  u16x4 gx[4];
#pragma unroll
  for (int g = 0; g < 4; ++g)
    gx[g] = *(const u16x4*)(wsu + G1X_U +
        ((((((size_t)0 * 256 + blkid) * 4 + lg) * 4 + g) * 8 + wid) * 16 + lr) * 4);

  __syncthreads();   // staging + Wl drained

  auto frag = [&](const u16* buf, int kg) -> bf16x8 {
    return *(const bf16x8*)&buf[(lr * 128 + kg * 8) ^ ((lr & 7) << 3)];
  };

  // ================= 32-step scan, 1 barrier/step =================
#pragma unroll 2
  for (int tl = 0; tl < TC; ++tl) {
    const int p = tl & 1, q = p ^ 1;

    // -- phase 1: cell1 = g1x(t) + Whh1 * h1(t-1) --
    f32x4 acc[4];
#pragma unroll
    for (int g = 0; g < 4; ++g)
      acc[g] = (f32x4){ b2f(gx[g][0]), b2f(gx[g][1]), b2f(gx[g][2]), b2f(gx[g][3]) };
    if (tl < TC - 1) {
#pragma unroll
      for (int g = 0; g < 4; ++g)
        gx[g] = *(const u16x4*)(wsu + G1X_U +
            ((((((size_t)(tl + 1) * 256 + blkid) * 4 + lg) * 4 + g) * 8 + wid) * 16 + lr) * 4);
    }
    bf16x8 h1f[4];
#pragma unroll
    for (int kf = 0; kf < 4; ++kf) h1f[kf] = frag(H1d[p], kf * 4 + lg);
#pragma unroll
    for (int kf = 0; kf < 4; ++kf)
#pragma unroll
      for (int g = 0; g < 4; ++g) acc[g] = MFMA16(h1f[kf], wA[g][kf], acc[g]);
    u16 hv[4];
#pragma unroll
    for (int j = 0; j < 4; ++j) {
      float cn = fsig(acc[1][j]) * cs1[j] + fsig(acc[0][j]) * ftanh(acc[2][j]);
      cs1[j] = cn;
      hv[j] = f2bf(fsig(acc[3][j]) * ftanh(cn));
    }
#pragma unroll
    for (int j = 0; j < 4; ++j) {
      int r = lg * 4 + j;
      H1d[q][(r * 128 + 16 * wid + lr) ^ ((r & 7) << 3)] = hv[j];
    }
    LGKM_BAR;   // h1(t) visible; all reads of H1d[p] complete

    // -- phase 2: cell2 = bs2 + Wih2 * h1(t) + Whh2 * h2(t-1) --
    f32x4 acd[4];
#pragma unroll
    for (int g = 0; g < 4; ++g) acd[g] = (f32x4){ bc2[g], bc2[g], bc2[g], bc2[g] };
#pragma unroll
    for (int kf = 0; kf < 4; ++kf) {
      bf16x8 h1n = frag(H1d[q], kf * 4 + lg);
#pragma unroll
      for (int g = 0; g < 4; ++g) acd[g] = MFMA16(h1n, wB[g][kf], acd[g]);
    }
#pragma unroll
    for (int kf = 0; kf < 4; ++kf) {
      bf16x8 h2f = frag(H2d[p], kf * 4 + lg);
#pragma unroll
      for (int g = 0; g < 4; ++g) {
        bf16x8 B = *(const bf16x8*)&Wl[(((wid * 4 + g) * 4 + kf) * 512) + lane * 8];
        acd[g] = MFMA16(h2f, B, acd[g]);
      }
    }
#pragma unroll
    for (int j = 0; j < 4; ++j) {
      float cn = fsig(acd[1][j]) * cs2[j] + fsig(acd[0][j]) * ftanh(acd[2][j]);
      cs2[j] = cn;
      hv[j] = f2bf(fsig(acd[3][j]) * ftanh(cn));
    }
#pragma unroll
    for (int j = 0; j < 4; ++j) {
      int r = lg * 4 + j;
      H2d[q][(r * 128 + 16 * wid + lr) ^ ((r & 7) << 3)] = hv[j];
    }
    // no second barrier (parity argument: see R8/R9)
  }
  LGKM_BAR;   // final h writes visible

  if (!last) {
    *(u16x4*)(wsu + STH1_U + (size_t)(b0 + r5) * 128 + c5) = *(const u16x4*)&H1d[0][swl];
    *(u16x4*)(wsu + STH2_U + (size_t)(b0 + r5) * 128 + c5) = *(const u16x4*)&H2d[0][swl];
#pragma unroll
    for (int j = 0; j < 4; ++j) {
      wsf[C1_F + (size_t)(b0 + lg * 4 + j) * 128 + 16 * wid + lr] = cs1[j];
      wsf[C2_F + (size_t)(b0 + lg * 4 + j) * 128 + 16 * wid + lr] = cs2[j];
    }
  } else {
    // ---- head: Y1 -> H1d[1]; Y2 -> H2d[1] (lo) | H1d[0] (hi); Y3 -> out ----
    {
      f32x4 y1 = {};
#pragma unroll
      for (int kf = 0; kf < 4; ++kf) {
        bf16x8 A = frag(H2d[0], kf * 4 + lg);
        bf16x8 B = *(const bf16x8*)(wsu + WO1_U + (size_t)((wid * 4 + kf) * 512) + lane * 8);
        y1 = MFMA16(A, B, y1);
      }
      float bo1 = b_out1[wid * 16 + lr];
      LGKM_BAR;
#pragma unroll
      for (int j = 0; j < 4; ++j) {
        int r = lg * 4 + j;
        H1d[1][(r * 128 + 16 * wid + lr) ^ ((r & 7) << 3)] = f2bf(fmaxf(y1[j] + bo1, 0.f));
      }
      LGKM_BAR;
    }
    {
      f32x4 y2[2] = {};
#pragma unroll
      for (int kf = 0; kf < 4; ++kf) {
        bf16x8 A = frag(H1d[1], kf * 4 + lg);
#pragma unroll
        for (int n = 0; n < 2; ++n) {
          bf16x8 B = *(const bf16x8*)(wsu + WO2_U + (size_t)(((2 * wid + n) * 4 + kf) * 512) + lane * 8);
          y2[n] = MFMA16(A, B, y2[n]);
        }
      }
      LGKM_BAR;
#pragma unroll
      for (int n = 0; n < 2; ++n)
#pragma unroll
        for (int j = 0; j < 4; ++j) {
          int c = (2 * wid + n) * 16 + lr;
          float v = fmaxf(y2[n][j] + b_out2[c], 0.f);
          u16* buf = (c < 128) ? &H2d[1][0] : &H1d[0][0];
          int cc = c & 127, r = lg * 4 + j;
          buf[(r * 128 + cc) ^ ((r & 7) << 3)] = f2bf(v);
        }
      LGKM_BAR;
    }
    if (wid < 2) {
      f32x4 y3 = {};
#pragma unroll
      for (int kf = 0; kf < 8; ++kf) {
        const u16* ab = (kf < 4) ? &H2d[1][0] : &H1d[0][0];
        bf16x8 A = frag(ab, (kf & 3) * 4 + lg);
        bf16x8 B = *(const bf16x8*)(wsu + WO3_U + (size_t)((wid * 8 + kf) * 512) + lane * 8);
        y3 = MFMA16(A, B, y3);
      }
      float bo3 = b_out3[wid * 16 + lr];
#pragma unroll
      for (int j = 0; j < 4; ++j)
        out[(size_t)(b0 + lg * 4 + j) * 32 + wid * 16 + lr] = y3[j] + bo3;
    }
  }
}

// ======================= host ==============================================
extern "C" void kernel_launch(void* const* d_in, const int* in_sizes, int n_in,
                              void* d_out, int out_size, void* d_ws, size_t ws_size,
                              hipStream_t stream) {
  (void)in_sizes; (void)n_in; (void)out_size; (void)ws_size;
  const float* seq    = (const float*)d_in[0];
  const float* h1     = (const float*)d_in[1];
  const float* c1     = (const float*)d_in[2];
  const float* h2     = (const float*)d_in[3];
  const float* c2     = (const float*)d_in[4];
  const float* W_in1  = (const float*)d_in[5];
  const float* b_in1  = (const float*)d_in[6];
  const float* W_in2  = (const float*)d_in[7];
  const float* b_in2  = (const float*)d_in[8];
  const float* W_in3  = (const float*)d_in[9];
  const float* b_in3  = (const float*)d_in[10];
  const float* Wih1   = (const float*)d_in[11];
  const float* Whh1   = (const float*)d_in[12];
  const float* bih1   = (const float*)d_in[13];
  const float* bhh1   = (const float*)d_in[14];
  const float* Wih2   = (const float*)d_in[15];
  const float* Whh2   = (const float*)d_in[16];
  const float* bih2   = (const float*)d_in[17];
  const float* bhh2   = (const float*)d_in[18];
  const float* W_out1 = (const float*)d_in[19];
  const float* b_out1 = (const float*)d_in[20];
  const float* W_out2 = (const float*)d_in[21];
  const float* b_out2 = (const float*)d_in[22];
  const float* W_out3 = (const float*)d_in[23];
  const float* b_out3 = (const float*)d_in[24];
  u16* wsu = (u16*)d_ws;
  float* out = (float*)d_out;

  hipLaunchKernelGGL(prep_kernel, dim3(512), dim3(256), 0, stream,
                     Wih1, Whh1, bih1, bhh1, Wih2, Whh2, bih2, bhh2,
                     W_in1, W_in2, W_in3, W_out1, W_out2, W_out3,
                     h1, h2, c1, c2, wsu);
  for (int k = 0; k < NCH; ++k) {
    hipLaunchKernelGGL(fc_chunk, dim3(2048), dim3(256), 0, stream,
                       seq, b_in1, b_in2, b_in3, wsu, k * TC);
    hipLaunchKernelGGL(scan_chunk, dim3(256), dim3(512), 0, stream,
                       wsu, out, b_out1, b_out2, b_out3, (k == NCH - 1) ? 1 : 0);
  }
}